// Round 14
// baseline (3553.279 us; speedup 1.0000x reference)
//
#include <hip/hip_runtime.h>
#include <math.h>

// LatentFNO: B=32, T=24, R=512, W=128, M=64 modes, 4 layers, 12 steps.
// Round 13: r13's barrier arrive was a 256-way serialized RMW on one cache
// line (~16us/barrier x157 = 2.5ms). New barrier: per-block release-STORE
// into own 128B slot (parallel), block0's 256 threads scan slots (poll >=
// gen, monotonic -> safe vs one-phase-ahead overwrite), block0 broadcasts
// generation; waiters poll relaxed + one acquire fence. Phase bodies
// byte-identical to r13 (math: exact 3-term bf16 split).

#define NB 32
#define NR 512
#define NW 128
#define NM 64
#define NTH 24
#define NLAY 4
#define NSTEPS 12
#define SEQROWS 36

typedef unsigned short u16;
typedef unsigned int u32;
typedef __attribute__((ext_vector_type(8))) short bf16x8;
typedef __attribute__((ext_vector_type(4))) float f32x4;
#define MFMA16(a, b, c) __builtin_amdgcn_mfma_f32_16x16x32_bf16((a), (b), (c), 0, 0, 0)

__device__ __forceinline__ float gelu_exact(float x) {
    return 0.5f * x * (1.0f + erff(x * 0.70710678118654752f));
}
__device__ __forceinline__ float bf2f(u16 u) {
    union { u32 i; float f; } v; v.i = ((u32)u) << 16; return v.f;
}
__device__ __forceinline__ u16 f2bf_hi(float x) {
    union { float f; u32 i; } v; v.f = x; return (u16)(v.i >> 16);
}
__device__ __forceinline__ u16 f2bf_lo(float x) {
    float h = bf2f(f2bf_hi(x));
    return f2bf_hi(x - h);
}
__device__ __forceinline__ bf16x8 negbf(bf16x8 a) {
#pragma unroll
    for (int i = 0; i < 8; i++) a[i] ^= (short)0x8000;
    return a;
}

// Grid barrier, slot-array arrive.
// bar[0] = generation line; bar[32*(1+bid)] = per-block slot (128B apart).
// gen passed by caller, strictly increasing from 1. Slots monotonic; poll
// uses >= so a block one phase ahead (slot overwritten to gen+1) is safe.
__device__ __forceinline__ void grid_barrier(unsigned* bar, unsigned gen) {
    __syncthreads();
    if (threadIdx.x == 0) {
        // release: wb L2 (cross-XCD visibility of this block's phase writes)
        __hip_atomic_store(&bar[32 * (1 + blockIdx.x)], gen,
                           __ATOMIC_RELEASE, __HIP_MEMORY_SCOPE_AGENT);
    }
    if (blockIdx.x == 0) {
        // thread t watches slot t (256 threads = 256 slots, parallel scan)
        while (__hip_atomic_load(&bar[32 * (1 + threadIdx.x)],
                                 __ATOMIC_RELAXED, __HIP_MEMORY_SCOPE_AGENT) < gen) {
            __builtin_amdgcn_s_sleep(1);
        }
        __syncthreads();
        if (threadIdx.x == 0) {
            __hip_atomic_store(&bar[0], gen, __ATOMIC_RELEASE, __HIP_MEMORY_SCOPE_AGENT);
        }
    } else {
        if (threadIdx.x == 0) {
            while (__hip_atomic_load(&bar[0], __ATOMIC_RELAXED,
                                     __HIP_MEMORY_SCOPE_AGENT) < gen) {
                __builtin_amdgcn_s_sleep(2);
            }
        }
    }
    if (threadIdx.x == 0) __builtin_amdgcn_fence(__ATOMIC_ACQUIRE, "agent");
    __syncthreads();
}

// ---------------------------------------------------------------------------
// Setup kernels (unchanged)
// ---------------------------------------------------------------------------
__global__ void build_tables_planes(u16* __restrict__ f1, u16* __restrict__ f2,
                                    u16* __restrict__ gt1, u16* __restrict__ gt2) {
    int idx = blockIdx.x * 256 + threadIdx.x;   // 65536: mc*512 + r
    int mc = idx >> 9, r = idx & 511, m = mc & 63;
    int p = (m * r) & 511;
    float a = (float)p * (1.0f / 256.0f);
    float c = cospif(a), s = sinpif(a);
    float Fv = (mc < 64) ? c : -s;
    float cm = (m == 0) ? (1.0f / 512.0f) : (2.0f / 512.0f);
    float Gv = (mc < 64) ? cm * c : ((m == 0) ? 0.0f : -cm * s);
    f1[idx] = f2bf_hi(Fv); f2[idx] = f2bf_lo(Fv);
    size_t g = (size_t)r * 128 + mc;
    gt1[g] = f2bf_hi(Gv); gt2[g] = f2bf_lo(Gv);
}

__global__ __launch_bounds__(256) void prep_specw(const float* __restrict__ wr, const float* __restrict__ wi,
                           u16* __restrict__ wr1, u16* __restrict__ wr2,
                           u16* __restrict__ wi1, u16* __restrict__ wi2) {
    __shared__ float tile[128][65];
    int l = blockIdx.x >> 7, o = blockIdx.x & 127;
    int tid = threadIdx.x;
    size_t sbase = (size_t)l * 1048576 + (size_t)o * 64;
    size_t dbase = (size_t)l * 64 * 16384 + (size_t)o * 128;
    for (int pass = 0; pass < 2; pass++) {
        const float* src = pass ? wi : wr;
        u16* d1 = pass ? wi1 : wr1;
        u16* d2 = pass ? wi2 : wr2;
        if (pass) __syncthreads();
        for (int e = tid; e < 8192; e += 256) {
            int i = e >> 6, m = e & 63;
            tile[i][m] = src[sbase + (size_t)i * 8192 + m];
        }
        __syncthreads();
        for (int e = tid; e < 4096; e += 256) {
            int m = e >> 6, i2 = (e & 63) * 2;
            float v0 = tile[i2][m], v1 = tile[i2 + 1][m];
            u32 hh = (u32)f2bf_hi(v0) | ((u32)f2bf_hi(v1) << 16);
            u32 ll = (u32)f2bf_lo(v0) | ((u32)f2bf_lo(v1) << 16);
            size_t d = dbase + (size_t)m * 16384 + i2;
            *(u32*)&d1[d] = hh;
            *(u32*)&d2[d] = ll;
        }
    }
}

__global__ void prep_cw(const float* __restrict__ cw, u16* __restrict__ c1, u16* __restrict__ c2) {
    int idx = blockIdx.x * 256 + threadIdx.x;   // 65536
    float v = cw[idx];
    c1[idx] = f2bf_hi(v); c2[idx] = f2bf_lo(v);
}

__global__ void prep_fc1t(const float* __restrict__ fc1_w,
                          u16* __restrict__ f11, u16* __restrict__ f12) {
    int idx = blockIdx.x * 256 + threadIdx.x;   // 32768: j*128 + c
    int j = idx >> 7, c = idx & 127;
    float v = fc1_w[(size_t)c * 256 + j];
    f11[idx] = f2bf_hi(v); f12[idx] = f2bf_lo(v);
}

__global__ void init_seq_kernel(const float* __restrict__ z, float* __restrict__ seq) {
    int idx = blockIdx.x * 256 + threadIdx.x;    // < 32*24*512
    int b = idx / (NTH * NR);
    int rem = idx - b * (NTH * NR);
    seq[(size_t)b * SEQROWS * NR + rem] = z[idx];
}

// ---------------------------------------------------------------------------
// Persistent kernel: whole 12-step rollout, 156 grid barriers.
// 256 blocks x 256 threads (1/CU). POOL = 70144 B shared, re-carved per phase.
// ---------------------------------------------------------------------------
struct PersistArgs {
    const u16 *f1, *f2, *gt1, *gt2;
    const u16 *wr1, *wr2, *wi1, *wi2;
    const u16 *cw1, *cw2;
    const float *conv_b;
    const u16 *f11, *f12;
    const float *fc1_b, *fc2_w, *fc2_b, *t_grid, *fc0_w, *fc0_b;
    float *seq, *preds;
    u16 *ht1, *ht2, *htc1, *htc2, *x1, *x2, *y1, *y2;
    unsigned *gbar;
};

__global__ __launch_bounds__(256, 1) void fno_persist(PersistArgs P) {
    __shared__ __align__(16) u16 POOL[35072];   // 70144 B
    const int bid = blockIdx.x;
    const int tid = threadIdx.x;
    const size_t htplane = (size_t)NB * NR * NW;
    unsigned gen = 0;

    // ======================= phase: fc0 (step 0) ===========================
    {
        float* wlds = (float*)POOL;             // 28*128
        float* blds = (float*)POOL + 3584;      // 128
        int b = bid >> 3, rblk = bid & 7;
        for (int t = tid; t < 28 * 128; t += 256) wlds[t] = P.fc0_w[t];
        if (tid < 128) blds[tid] = P.fc0_b[tid];
        __syncthreads();
        int lane = tid & 63, wq = tid >> 6;
        int r = rblk * 64 + lane;
        float sv[24];
        const float* sp = P.seq + ((size_t)b * SEQROWS + 0) * NR + r;
#pragma unroll
        for (int t = 0; t < 24; t++) sv[t] = sp[(size_t)t * NR];
        float tt = P.t_grid[b * 24 + 23] + 1.0f;
        float ang24 = 6.28318530717958647692f * tt * (1.0f / 24.0f);
        float ang168 = 6.28318530717958647692f * tt * (1.0f / 168.0f);
        float s24 = sinf(ang24), c24 = cosf(ang24), s168 = sinf(ang168);
        float xc = (float)r * (1.0f / 511.0f);
        size_t rowoff = ((size_t)b * NR + r) * NW;
#pragma unroll 2
        for (int w0 = 0; w0 < 32; w0 += 2) {
            float acc2[2];
#pragma unroll
            for (int q = 0; q < 2; q++) {
                int w = wq * 32 + w0 + q;
                float acc = blds[w];
#pragma unroll
                for (int t = 0; t < 24; t++) acc += sv[t] * wlds[t * 128 + w];
                acc += s24 * wlds[24 * 128 + w] + c24 * wlds[25 * 128 + w]
                     + s168 * wlds[26 * 128 + w] + xc * wlds[27 * 128 + w];
                acc2[q] = acc;
            }
            u16 h0 = f2bf_hi(acc2[0]), h1 = f2bf_hi(acc2[1]);
            u16 l0 = f2bf_lo(acc2[0]), l1 = f2bf_lo(acc2[1]);
            size_t off = rowoff + wq * 32 + w0;
            *(u32*)&P.ht1[off] = (u32)h0 | ((u32)h1 << 16);
            *(u32*)&P.ht2[off] = (u32)l0 | ((u32)l1 << 16);
            int w = wq * 32 + w0;
            size_t coff = ((size_t)b * 128 + w) * 512 + r;
            P.htc1[coff] = h0; P.htc1[coff + 512] = h1;
            P.htc2[coff] = l0; P.htc2[coff + 512] = l1;
        }
    }
    grid_barrier(P.gbar, ++gen);

    for (int step = 0; step < NSTEPS; step++) {
        int cur = 0;
        for (int ly = 0; ly < NLAY; ly++) {
            // ======================= phase: dft ============================
            {
                u16* A1 = POOL;                  // [2][1280]
                u16* A2 = POOL + 2560;
                u16* B1 = POOL + 5120;           // [2][2560]
                u16* B2 = POOL + 10240;
                int bx = bid & 63;
                int mct = (bid >> 6) * 32;
                int b = bx >> 1, ch = bx & 1;
                int wid = tid >> 6, l = tid & 63;
                int wm0 = (wid >> 1) * 16, wn0 = (wid & 1) * 32;
                int arow = (l & 15), kgrp = (l >> 4) * 8;
                f32x4 acc0 = {0.f, 0.f, 0.f, 0.f}, acc1 = {0.f, 0.f, 0.f, 0.f};
                int pa_pl = tid >> 7, pa_row = (tid >> 2) & 31, pa_seg = tid & 3;
                const u16* asrc = (pa_pl ? P.f2 : P.f1) + (size_t)(mct + pa_row) * 512 + pa_seg * 8;
                int aoff = pa_row * 40 + pa_seg * 8;
                int b_row = (tid >> 2) & 63, b_seg = tid & 3;
                const u16* bsrc1 = P.htc1 + ((size_t)b * 128 + ch * 64 + b_row) * 512 + b_seg * 8;
                const u16* bsrc2 = P.htc2 + ((size_t)b * 128 + ch * 64 + b_row) * 512 + b_seg * 8;
                int boff = b_row * 40 + b_seg * 8;
                u16* adst = (pa_pl ? A2 : A1) + aoff;
                uint4 raO, rbO0, rbO1, raE, rbE0, rbE1;
                raO = *(const uint4*)(asrc); rbO0 = *(const uint4*)(bsrc1); rbO1 = *(const uint4*)(bsrc2);
                *(uint4*)(adst) = raO;
                *(uint4*)(B1 + boff) = rbO0;
                *(uint4*)(B2 + boff) = rbO1;
                raO = *(const uint4*)(asrc + 32); rbO0 = *(const uint4*)(bsrc1 + 32); rbO1 = *(const uint4*)(bsrc2 + 32);
                raE = *(const uint4*)(asrc + 64); rbE0 = *(const uint4*)(bsrc1 + 64); rbE1 = *(const uint4*)(bsrc2 + 64);
                __syncthreads();
#define DFT_COMPUTE(BUF)                                                             \
    {   bf16x8 a1 = *(const bf16x8*)&A1[(BUF) * 1280 + (wm0 + arow) * 40 + kgrp];    \
        bf16x8 a2 = *(const bf16x8*)&A2[(BUF) * 1280 + (wm0 + arow) * 40 + kgrp];    \
        bf16x8 b10 = *(const bf16x8*)&B1[(BUF) * 2560 + (wn0 + arow) * 40 + kgrp];   \
        bf16x8 b20 = *(const bf16x8*)&B2[(BUF) * 2560 + (wn0 + arow) * 40 + kgrp];   \
        bf16x8 b11 = *(const bf16x8*)&B1[(BUF) * 2560 + (wn0 + 16 + arow) * 40 + kgrp]; \
        bf16x8 b21 = *(const bf16x8*)&B2[(BUF) * 2560 + (wn0 + 16 + arow) * 40 + kgrp]; \
        acc0 = MFMA16(a1, b10, acc0);                                                \
        acc0 = MFMA16(a1, b20, acc0);                                                \
        acc0 = MFMA16(a2, b10, acc0);                                                \
        acc1 = MFMA16(a1, b11, acc1);                                                \
        acc1 = MFMA16(a1, b21, acc1);                                                \
        acc1 = MFMA16(a2, b11, acc1); }
                for (int k = 0; k < 16; k += 2) {
                    DFT_COMPUTE(0)
                    *(uint4*)(adst + 1280) = raO;
                    *(uint4*)(B1 + 2560 + boff) = rbO0;
                    *(uint4*)(B2 + 2560 + boff) = rbO1;
                    if (k < 13) {
                        int ko = (k + 3) * 32;
                        raO = *(const uint4*)(asrc + ko); rbO0 = *(const uint4*)(bsrc1 + ko); rbO1 = *(const uint4*)(bsrc2 + ko);
                    }
                    __syncthreads();
                    DFT_COMPUTE(1)
                    if (k < 14) {
                        *(uint4*)(adst) = raE;
                        *(uint4*)(B1 + boff) = rbE0;
                        *(uint4*)(B2 + boff) = rbE1;
                        if (k < 12) {
                            int ko = (k + 4) * 32;
                            raE = *(const uint4*)(asrc + ko); rbE0 = *(const uint4*)(bsrc1 + ko); rbE1 = *(const uint4*)(bsrc2 + ko);
                        }
                    }
                    __syncthreads();
                }
#undef DFT_COMPUTE
                int mcr = mct + wm0 + (l >> 4) * 4;
                int n0 = bx * 64 + wn0 + (l & 15);
#pragma unroll
                for (int j = 0; j < 4; j++) {
                    size_t o0 = (size_t)(mcr + j) * 4096 + n0;
                    P.x1[o0] = f2bf_hi(acc0[j]); P.x2[o0] = f2bf_lo(acc0[j]);
                    size_t o1 = o0 + 16;
                    P.x1[o1] = f2bf_hi(acc1[j]); P.x2[o1] = f2bf_lo(acc1[j]);
                }
            }
            grid_barrier(P.gbar, ++gen);

            // ======================= phase: modemix ========================
            {
                int m = bid & 63, oq = bid >> 6;
                int wid = tid >> 6, l = tid & 63;
                int wo0 = (wid >> 1) * 16, wb0 = (wid & 1) * 16;
                int arow = l & 15, kgrp = (l >> 4) * 8;
                size_t wbase = (((size_t)ly * 64 + m) * 128 + oq * 32) * 128;
#pragma unroll
                for (int q = 0; q < 16; q++) {
                    const int slab = q >> 1;
                    int rr = ((q & 1) << 4) + (tid >> 4);
                    int seg = tid & 15;
                    const u16* src;
                    if      (slab == 0) src = P.wr1 + wbase + (size_t)rr * 128 + seg * 8;
                    else if (slab == 1) src = P.wr2 + wbase + (size_t)rr * 128 + seg * 8;
                    else if (slab == 2) src = P.wi1 + wbase + (size_t)rr * 128 + seg * 8;
                    else if (slab == 3) src = P.wi2 + wbase + (size_t)rr * 128 + seg * 8;
                    else if (slab == 4) src = P.x1 + (size_t)m * 4096 + rr * 128 + seg * 8;
                    else if (slab == 5) src = P.x2 + (size_t)m * 4096 + rr * 128 + seg * 8;
                    else if (slab == 6) src = P.x1 + (size_t)(64 + m) * 4096 + rr * 128 + seg * 8;
                    else                src = P.x2 + (size_t)(64 + m) * 4096 + rr * 128 + seg * 8;
                    *(uint4*)&POOL[slab * 4352 + rr * 136 + seg * 8] = *(const uint4*)src;
                }
                __syncthreads();
                f32x4 ar = {0.f, 0.f, 0.f, 0.f}, ai = {0.f, 0.f, 0.f, 0.f};
                int aoB = (wo0 + arow) * 136 + kgrp;
                int boB = (wb0 + arow) * 136 + kgrp;
#pragma unroll
                for (int kg = 0; kg < 4; kg++) {
                    int ao = aoB + kg * 32;
                    int bo = boB + kg * 32;
                    bf16x8 Wr1 = *(const bf16x8*)&POOL[0 * 4352 + ao];
                    bf16x8 Wr2 = *(const bf16x8*)&POOL[1 * 4352 + ao];
                    bf16x8 Wi1 = *(const bf16x8*)&POOL[2 * 4352 + ao];
                    bf16x8 Wi2 = *(const bf16x8*)&POOL[3 * 4352 + ao];
                    bf16x8 Xr1 = *(const bf16x8*)&POOL[4 * 4352 + bo];
                    bf16x8 Xr2 = *(const bf16x8*)&POOL[5 * 4352 + bo];
                    bf16x8 Xi1 = *(const bf16x8*)&POOL[6 * 4352 + bo];
                    bf16x8 Xi2 = *(const bf16x8*)&POOL[7 * 4352 + bo];
                    bf16x8 nWi1 = negbf(Wi1), nWi2 = negbf(Wi2);
                    ar = MFMA16(Wr1, Xr1, ar); ar = MFMA16(Wr1, Xr2, ar); ar = MFMA16(Wr2, Xr1, ar);
                    ar = MFMA16(nWi1, Xi1, ar); ar = MFMA16(nWi1, Xi2, ar); ar = MFMA16(nWi2, Xi1, ar);
                    ai = MFMA16(Wi1, Xr1, ai); ai = MFMA16(Wi1, Xr2, ai); ai = MFMA16(Wi2, Xr1, ai);
                    ai = MFMA16(Wr1, Xi1, ai); ai = MFMA16(Wr1, Xi2, ai); ai = MFMA16(Wr2, Xi1, ai);
                }
                int ob = oq * 32 + wo0 + (l >> 4) * 4;
                int bb = wb0 + (l & 15);
#pragma unroll
                for (int j = 0; j < 4; j++) {
                    size_t o = ((size_t)bb * 128 + ob + j) * 128;
                    P.y1[o + m] = f2bf_hi(ar[j]); P.y2[o + m] = f2bf_lo(ar[j]);
                    P.y1[o + 64 + m] = f2bf_hi(ai[j]); P.y2[o + 64 + m] = f2bf_lo(ai[j]);
                }
            }
            grid_barrier(P.gbar, ++gen);

            // ======================= phase: idft+conv ======================
            {
                const u16* hc1 = P.ht1 + (size_t)cur * htplane;
                const u16* hc2 = P.ht2 + (size_t)cur * htplane;
                u16* hn1 = P.ht1 + (size_t)(cur ^ 1) * htplane;
                u16* hn2 = P.ht2 + (size_t)(cur ^ 1) * htplane;
                int wtr = (ly < 3) ? 1 : 0;
                u16* A1 = POOL;                  // [2][128*40] = 10240
                u16* A2 = POOL + 10240;
                u16* B1 = POOL + 20480;          // [2][64*40] = 5120
                u16* B2 = POOL + 25600;
                int rt = (bid & 7) * 64, b = bid >> 3;
                int wid = tid >> 6, l = tid & 63;
                int wo0 = (wid >> 1) * 32, wr0 = (wid & 1) * 32;
                int arow = (l & 15), kgrp = (l >> 4) * 8;
                int srow = tid >> 2, sseg = tid & 3;       // srow 0..63
                const u16* ya0 = P.y1 + ((size_t)b * 128 + srow) * 128 + sseg * 8;
                const u16* ya1 = ya0 + 64 * 128;
                const u16* yb0 = P.y2 + ((size_t)b * 128 + srow) * 128 + sseg * 8;
                const u16* yb1 = yb0 + 64 * 128;
                const u16* ca0 = P.cw1 + ((size_t)ly * 128 + srow) * 128 + sseg * 8;
                const u16* ca1 = ca0 + 64 * 128;
                const u16* cb0 = P.cw2 + ((size_t)ly * 128 + srow) * 128 + sseg * 8;
                const u16* cb1 = cb0 + 64 * 128;
                const u16* ga = P.gt1 + (size_t)(rt + srow) * 128 + sseg * 8;
                const u16* gb = P.gt2 + (size_t)(rt + srow) * 128 + sseg * 8;
                const u16* ha = hc1 + ((size_t)b * 512 + rt + srow) * 128 + sseg * 8;
                const u16* hb = hc2 + ((size_t)b * 512 + rt + srow) * 128 + sseg * 8;
                int soffA0 = srow * 40 + sseg * 8;
                int soffA1 = (srow + 64) * 40 + sseg * 8;
                f32x4 acc[2][2][2];
#pragma unroll
                for (int ot = 0; ot < 2; ot++)
#pragma unroll
                    for (int of = 0; of < 2; of++)
#pragma unroll
                        for (int rf = 0; rf < 2; rf++) acc[ot][of][rf] = (f32x4){0.f, 0.f, 0.f, 0.f};
                uint4 oA0, oA1r, oA2r, oA3, oB0, oB1;
                uint4 eA0, eA1r, eA2r, eA3, eB0, eB1;
#define ILOAD(chk, Q0, Q1, Q2, Q3, R0, R1)                                    \
    {   int k0_ = ((chk) & 3) * 32;                                           \
        if ((chk) < 4) {                                                      \
            Q0 = *(const uint4*)(ya0 + k0_); Q1 = *(const uint4*)(ya1 + k0_); \
            Q2 = *(const uint4*)(yb0 + k0_); Q3 = *(const uint4*)(yb1 + k0_); \
            R0 = *(const uint4*)(ga + k0_);  R1 = *(const uint4*)(gb + k0_);  \
        } else {                                                              \
            Q0 = *(const uint4*)(ca0 + k0_); Q1 = *(const uint4*)(ca1 + k0_); \
            Q2 = *(const uint4*)(cb0 + k0_); Q3 = *(const uint4*)(cb1 + k0_); \
            R0 = *(const uint4*)(ha + k0_);  R1 = *(const uint4*)(hb + k0_);  \
        } }
#define ISTORE(BUF, Q0, Q1, Q2, Q3, R0, R1)                                   \
    {   *(uint4*)(A1 + (BUF) * 5120 + soffA0) = Q0;                           \
        *(uint4*)(A1 + (BUF) * 5120 + soffA1) = Q1;                           \
        *(uint4*)(A2 + (BUF) * 5120 + soffA0) = Q2;                           \
        *(uint4*)(A2 + (BUF) * 5120 + soffA1) = Q3;                           \
        *(uint4*)(B1 + (BUF) * 2560 + soffA0) = R0;                           \
        *(uint4*)(B2 + (BUF) * 2560 + soffA0) = R1; }
#define ICOMP(BUF)                                                            \
    {   bf16x8 bfr[2][2];                                                     \
        _Pragma("unroll")                                                     \
        for (int rf = 0; rf < 2; rf++) {                                      \
            bfr[rf][0] = *(const bf16x8*)&B1[(BUF) * 2560 + (wr0 + rf * 16 + arow) * 40 + kgrp]; \
            bfr[rf][1] = *(const bf16x8*)&B2[(BUF) * 2560 + (wr0 + rf * 16 + arow) * 40 + kgrp]; \
        }                                                                     \
        _Pragma("unroll")                                                     \
        for (int ot = 0; ot < 2; ot++) {                                      \
        _Pragma("unroll")                                                     \
        for (int of = 0; of < 2; of++) {                                      \
            bf16x8 a1v = *(const bf16x8*)&A1[(BUF) * 5120 + (ot * 64 + wo0 + of * 16 + arow) * 40 + kgrp]; \
            bf16x8 a2v = *(const bf16x8*)&A2[(BUF) * 5120 + (ot * 64 + wo0 + of * 16 + arow) * 40 + kgrp]; \
            _Pragma("unroll")                                                 \
            for (int rf = 0; rf < 2; rf++) {                                  \
                acc[ot][of][rf] = MFMA16(a1v, bfr[rf][0], acc[ot][of][rf]);   \
                acc[ot][of][rf] = MFMA16(a1v, bfr[rf][1], acc[ot][of][rf]);   \
                acc[ot][of][rf] = MFMA16(a2v, bfr[rf][0], acc[ot][of][rf]);   \
            }                                                                 \
        } } }
                ILOAD(0, oA0, oA1r, oA2r, oA3, oB0, oB1)
                ISTORE(0, oA0, oA1r, oA2r, oA3, oB0, oB1)
                ILOAD(1, oA0, oA1r, oA2r, oA3, oB0, oB1)
                ILOAD(2, eA0, eA1r, eA2r, eA3, eB0, eB1)
                __syncthreads();
                for (int k = 0; k < 8; k += 2) {
                    ICOMP(0)
                    ISTORE(1, oA0, oA1r, oA2r, oA3, oB0, oB1)
                    if (k < 5) ILOAD(k + 3, oA0, oA1r, oA2r, oA3, oB0, oB1)
                    __syncthreads();
                    ICOMP(1)
                    if (k < 6) {
                        ISTORE(0, eA0, eA1r, eA2r, eA3, eB0, eB1)
                        if (k < 4) ILOAD(k + 4, eA0, eA1r, eA2r, eA3, eB0, eB1)
                    }
                    __syncthreads();
                }
#undef ILOAD
#undef ISTORE
#undef ICOMP
                __syncthreads();    // all LDS reads done; alias T over POOL
                u16* T1 = POOL;             // 128*66 = 8448
                u16* T2 = POOL + 8448;
#pragma unroll
                for (int ot = 0; ot < 2; ot++) {
#pragma unroll
                    for (int of = 0; of < 2; of++) {
                        int obl = ot * 64 + wo0 + of * 16 + (l >> 4) * 4;
#pragma unroll
                        for (int rf = 0; rf < 2; rf++) {
                            int rloc = wr0 + rf * 16 + (l & 15);
                            int r = rt + rloc;
                            float v0 = gelu_exact(acc[ot][of][rf][0] + P.conv_b[ly * 128 + obl + 0]);
                            float v1 = gelu_exact(acc[ot][of][rf][1] + P.conv_b[ly * 128 + obl + 1]);
                            float v2 = gelu_exact(acc[ot][of][rf][2] + P.conv_b[ly * 128 + obl + 2]);
                            float v3 = gelu_exact(acc[ot][of][rf][3] + P.conv_b[ly * 128 + obl + 3]);
                            ushort4 hv, lv;
                            hv.x = f2bf_hi(v0); hv.y = f2bf_hi(v1); hv.z = f2bf_hi(v2); hv.w = f2bf_hi(v3);
                            lv.x = f2bf_lo(v0); lv.y = f2bf_lo(v1); lv.z = f2bf_lo(v2); lv.w = f2bf_lo(v3);
                            size_t off = ((size_t)b * 512 + r) * 128 + obl;
                            *(ushort4*)&hn1[off] = hv;
                            *(ushort4*)&hn2[off] = lv;
                            if (wtr) {
                                T1[(obl + 0) * 66 + rloc] = hv.x; T1[(obl + 1) * 66 + rloc] = hv.y;
                                T1[(obl + 2) * 66 + rloc] = hv.z; T1[(obl + 3) * 66 + rloc] = hv.w;
                                T2[(obl + 0) * 66 + rloc] = lv.x; T2[(obl + 1) * 66 + rloc] = lv.y;
                                T2[(obl + 2) * 66 + rloc] = lv.z; T2[(obl + 3) * 66 + rloc] = lv.w;
                            }
                        }
                    }
                }
                if (wtr) {
                    __syncthreads();
#pragma unroll
                    for (int q = 0; q < 16; q++) {
                        int t = tid + q * 256;
                        int o = t >> 5, ru = t & 31;
                        u32 vh = *(const u32*)&T1[o * 66 + ru * 2];
                        u32 vl = *(const u32*)&T2[o * 66 + ru * 2];
                        size_t off = ((size_t)b * 128 + o) * 512 + rt + ru * 2;
                        *(u32*)&P.htc1[off] = vh;
                        *(u32*)&P.htc2[off] = vl;
                    }
                }
            }
            grid_barrier(P.gbar, ++gen);
            cur ^= 1;
        }

        // ======================= phase: head (+fc0 next) ===================
        {
            int do_fc0 = (step < NSTEPS - 1) ? 1 : 0;
            u16* HA1 = POOL;                // 256*40
            u16* HA2 = POOL + 10240;
            u16* HB1 = POOL + 20480;        // 64*40
            u16* HB2 = POOL + 23040;
            float* fc2s = (float*)(POOL + 26624);   // 256 f
            float* fc1bs = (float*)(POOL + 27136);  // 256 f
            int b = bid >> 3, r0 = (bid & 7) * 64;
            int wid = tid >> 6, l = tid & 63;
            fc2s[tid] = P.fc2_w[tid];
            fc1bs[tid] = P.fc1_b[tid];
            int arow = l & 15, kgrp = (l >> 4) * 8;
            f32x4 acc[16];
#pragma unroll
            for (int jf = 0; jf < 16; jf++) acc[jf] = (f32x4){0.f, 0.f, 0.f, 0.f};
            for (int k0 = 0; k0 < 128; k0 += 32) {
                __syncthreads();
#pragma unroll
                for (int q = 0; q < 8; q++) {
                    int t = tid + q * 256;
                    int pl = t >> 10, j = (t >> 2) & 255, seg = t & 3;
                    const u16* src = (pl ? P.f12 : P.f11) + (size_t)j * 128 + k0 + seg * 8;
                    *(uint4*)((pl ? HA2 : HA1) + j * 40 + seg * 8) = *(const uint4*)src;
                }
#pragma unroll
                for (int q = 0; q < 2; q++) {
                    int t = tid + q * 256;
                    int pl = t >> 8, rr = (t >> 2) & 63, seg = t & 3;
                    const u16* src = (pl ? P.ht2 : P.ht1) + ((size_t)b * 512 + r0 + rr) * 128 + k0 + seg * 8;
                    *(uint4*)((pl ? HB2 : HB1) + rr * 40 + seg * 8) = *(const uint4*)src;
                }
                __syncthreads();
                int bo = (wid * 16 + arow) * 40 + kgrp;
                bf16x8 b1 = *(const bf16x8*)&HB1[bo];
                bf16x8 b2 = *(const bf16x8*)&HB2[bo];
#pragma unroll
                for (int jf = 0; jf < 16; jf++) {
                    int ao = (jf * 16 + arow) * 40 + kgrp;
                    bf16x8 a1 = *(const bf16x8*)&HA1[ao];
                    bf16x8 a2 = *(const bf16x8*)&HA2[ao];
                    acc[jf] = MFMA16(a1, b1, acc[jf]);
                    acc[jf] = MFMA16(a1, b2, acc[jf]);
                    acc[jf] = MFMA16(a2, b1, acc[jf]);
                }
            }
            __syncthreads();
            float dx = 0.0f;
#pragma unroll
            for (int jf = 0; jf < 16; jf++) {
                int jbase = jf * 16 + (l >> 4) * 4;
#pragma unroll
                for (int jj = 0; jj < 4; jj++) {
                    int j = jbase + jj;
                    dx += gelu_exact(acc[jf][jj] + fc1bs[j]) * fc2s[j];
                }
            }
            dx += __shfl_xor(dx, 16);
            dx += __shfl_xor(dx, 32);
            bool zlane = ((l >> 4) == 0);
            int rml = wid * 16 + arow;
            float zn = 0.0f;
            if (zlane) {
                int r = r0 + rml;
                zn = P.seq[((size_t)b * SEQROWS + step + 23) * NR + r] + dx + P.fc2_b[0];
                P.seq[((size_t)b * SEQROWS + step + 24) * NR + r] = zn;
                P.preds[((size_t)b * NSTEPS + step) * NR + r] = zn;
            }
            if (do_fc0) {
                float* win = (float*)POOL;                 // [24][64]
                float* wl  = (float*)POOL + 2048;          // [28][128]
                float* bl  = (float*)POOL + 2048 + 3584;   // [128]
                __syncthreads();   // dx-phase LDS reads done before aliasing
                for (int t = tid; t < 23 * 64; t += 256) {
                    int tr = t >> 6, c = t & 63;
                    win[tr * 64 + c] = P.seq[((size_t)b * SEQROWS + step + 1 + tr) * NR + r0 + c];
                }
                for (int t = tid; t < 28 * 128; t += 256) wl[t] = P.fc0_w[t];
                if (tid < 128) bl[tid] = P.fc0_b[tid];
                if (zlane) win[23 * 64 + rml] = zn;
                __syncthreads();
                int lane = tid & 63, wq = tid >> 6;
                int r = r0 + lane;
                float sv[24];
#pragma unroll
                for (int t = 0; t < 24; t++) sv[t] = win[t * 64 + lane];
                float tt = P.t_grid[b * 24 + 23] + (float)(step + 2);
                float ang24 = 6.28318530717958647692f * tt * (1.0f / 24.0f);
                float ang168 = 6.28318530717958647692f * tt * (1.0f / 168.0f);
                float s24 = sinf(ang24), c24 = cosf(ang24), s168 = sinf(ang168);
                float xc = (float)r * (1.0f / 511.0f);
                size_t rowoff = ((size_t)b * NR + r) * NW;
#pragma unroll 2
                for (int w0 = 0; w0 < 32; w0 += 2) {
                    float acc2[2];
#pragma unroll
                    for (int q = 0; q < 2; q++) {
                        int w = wq * 32 + w0 + q;
                        float a = bl[w];
#pragma unroll
                        for (int t = 0; t < 24; t++) a += sv[t] * wl[t * 128 + w];
                        a += s24 * wl[24 * 128 + w] + c24 * wl[25 * 128 + w]
                           + s168 * wl[26 * 128 + w] + xc * wl[27 * 128 + w];
                        acc2[q] = a;
                    }
                    u16 h0 = f2bf_hi(acc2[0]), h1 = f2bf_hi(acc2[1]);
                    u16 l0 = f2bf_lo(acc2[0]), l1 = f2bf_lo(acc2[1]);
                    size_t off = rowoff + wq * 32 + w0;
                    *(u32*)&P.ht1[off] = (u32)h0 | ((u32)h1 << 16);
                    *(u32*)&P.ht2[off] = (u32)l0 | ((u32)l1 << 16);
                    int w = wq * 32 + w0;
                    size_t coff = ((size_t)b * 128 + w) * 512 + r;
                    P.htc1[coff] = h0; P.htc1[coff + 512] = h1;
                    P.htc2[coff] = l0; P.htc2[coff + 512] = l1;
                }
            }
        }
        if (step < NSTEPS - 1) grid_barrier(P.gbar, ++gen);
    }
}

// ---------------------------------------------------------------------------
extern "C" void kernel_launch(void* const* d_in, const int* in_sizes, int n_in,
                              void* d_out, int out_size, void* d_ws, size_t ws_size,
                              hipStream_t stream) {
    (void)in_sizes; (void)n_in; (void)out_size; (void)ws_size;
    const float* z       = (const float*)d_in[0];
    const float* t_grid  = (const float*)d_in[1];
    const float* fc0_w   = (const float*)d_in[2];
    const float* fc0_b   = (const float*)d_in[3];
    const float* spec_wr = (const float*)d_in[4];
    const float* spec_wi = (const float*)d_in[5];
    const float* conv_w  = (const float*)d_in[6];
    const float* conv_b  = (const float*)d_in[7];
    const float* fc1_w   = (const float*)d_in[8];
    const float* fc1_b   = (const float*)d_in[9];
    const float* fc2_w   = (const float*)d_in[10];
    const float* fc2_b   = (const float*)d_in[11];
    float* preds = (float*)d_out;

    char* p = (char*)d_ws;
    float* seq = (float*)p;  p += (size_t)NB * SEQROWS * NR * 4;
    u16* ht1 = (u16*)p;  p += (size_t)2 * NB * NR * NW * 2;   // [2 buf][b][r][c] hi
    u16* ht2 = (u16*)p;  p += (size_t)2 * NB * NR * NW * 2;   // lo
    u16* htc1 = (u16*)p; p += (size_t)NB * NW * NR * 2;       // [b][c][r] hi
    u16* htc2 = (u16*)p; p += (size_t)NB * NW * NR * 2;       // lo
    u16* x1  = (u16*)p;  p += (size_t)128 * 4096 * 2;
    u16* x2  = (u16*)p;  p += (size_t)128 * 4096 * 2;
    u16* y1  = (u16*)p;  p += (size_t)NB * NW * 128 * 2;
    u16* y2  = (u16*)p;  p += (size_t)NB * NW * 128 * 2;
    u16* f1  = (u16*)p;  p += (size_t)128 * 512 * 2;
    u16* f2  = (u16*)p;  p += (size_t)128 * 512 * 2;
    u16* gt1 = (u16*)p;  p += (size_t)512 * 128 * 2;
    u16* gt2 = (u16*)p;  p += (size_t)512 * 128 * 2;
    u16* wr1 = (u16*)p;  p += (size_t)NLAY * NM * NW * NW * 2;
    u16* wr2 = (u16*)p;  p += (size_t)NLAY * NM * NW * NW * 2;
    u16* wi1 = (u16*)p;  p += (size_t)NLAY * NM * NW * NW * 2;
    u16* wi2 = (u16*)p;  p += (size_t)NLAY * NM * NW * NW * 2;
    u16* cw1 = (u16*)p;  p += (size_t)NLAY * NW * NW * 2;
    u16* cw2 = (u16*)p;  p += (size_t)NLAY * NW * NW * 2;
    u16* f11 = (u16*)p;  p += (size_t)256 * 128 * 2;
    u16* f12 = (u16*)p;  p += (size_t)256 * 128 * 2;
    unsigned* gbar = (unsigned*)p; p += (size_t)(1 + 256) * 32 * 4;   // gen + 256 slots

    hipMemsetAsync(gbar, 0, (size_t)(1 + 256) * 32 * 4, stream);
    build_tables_planes<<<256, 256, 0, stream>>>(f1, f2, gt1, gt2);
    prep_specw<<<512, 256, 0, stream>>>(spec_wr, spec_wi, wr1, wr2, wi1, wi2);
    prep_cw<<<256, 256, 0, stream>>>(conv_w, cw1, cw2);
    prep_fc1t<<<128, 256, 0, stream>>>(fc1_w, f11, f12);
    init_seq_kernel<<<(NB * NTH * NR) / 256, 256, 0, stream>>>(z, seq);

    PersistArgs P;
    P.f1 = f1; P.f2 = f2; P.gt1 = gt1; P.gt2 = gt2;
    P.wr1 = wr1; P.wr2 = wr2; P.wi1 = wi1; P.wi2 = wi2;
    P.cw1 = cw1; P.cw2 = cw2; P.conv_b = conv_b;
    P.f11 = f11; P.f12 = f12;
    P.fc1_b = fc1_b; P.fc2_w = fc2_w; P.fc2_b = fc2_b;
    P.t_grid = t_grid; P.fc0_w = fc0_w; P.fc0_b = fc0_b;
    P.seq = seq; P.preds = preds;
    P.ht1 = ht1; P.ht2 = ht2; P.htc1 = htc1; P.htc2 = htc2;
    P.x1 = x1; P.x2 = x2; P.y1 = y1; P.y2 = y2;
    P.gbar = gbar;
    fno_persist<<<dim3(256), dim3(256), 0, stream>>>(P);
}

// Round 15
// 1760.953 us; speedup vs baseline: 2.0178x; 2.0178x over previous
//
#include <hip/hip_runtime.h>
#include <math.h>

// LatentFNO: B=32, T=24, R=512, W=128, M=64 modes, 4 layers, 12 steps.
// Round 14: persistent-kernel direction abandoned (two falsified barrier
// theories; phase bodies are cache-invalidation-bound). Reverted to the
// r9 multi-kernel structure (1809us measured) with two dispatch-count
// reductions: (a) head+fc0next fused into layer-3 idft (h tile stays in
// LDS; bit-identical j/k order); (b) 4 small setup kernels merged into 1.
// 162 -> 147 dispatches. Math: exact 3-term bf16 split (A1B1+A1B2+A2B1).

#define NB 32
#define NR 512
#define NW 128
#define NM 64
#define NTH 24
#define NLAY 4
#define NSTEPS 12
#define SEQROWS 36

typedef unsigned short u16;
typedef unsigned int u32;
typedef __attribute__((ext_vector_type(8))) short bf16x8;
typedef __attribute__((ext_vector_type(4))) float f32x4;
#define MFMA16(a, b, c) __builtin_amdgcn_mfma_f32_16x16x32_bf16((a), (b), (c), 0, 0, 0)

__device__ __forceinline__ float gelu_exact(float x) {
    return 0.5f * x * (1.0f + erff(x * 0.70710678118654752f));
}
__device__ __forceinline__ float bf2f(u16 u) {
    union { u32 i; float f; } v; v.i = ((u32)u) << 16; return v.f;
}
__device__ __forceinline__ u16 f2bf_hi(float x) {
    union { float f; u32 i; } v; v.f = x; return (u16)(v.i >> 16);
}
__device__ __forceinline__ u16 f2bf_lo(float x) {
    float h = bf2f(f2bf_hi(x));
    return f2bf_hi(x - h);
}
__device__ __forceinline__ bf16x8 negbf(bf16x8 a) {
#pragma unroll
    for (int i = 0; i < 8; i++) a[i] ^= (short)0x8000;
    return a;
}

// ---------------------------------------------------------------------------
// Merged setup: DFT/iDFT tables + conv_w planes + fc1t planes + seq init.
// grid 2176 x 256 covers 557056 linear work items.
// ---------------------------------------------------------------------------
__global__ void setup_misc(const float* __restrict__ z, const float* __restrict__ conv_w,
                           const float* __restrict__ fc1_w,
                           u16* __restrict__ f1, u16* __restrict__ f2,
                           u16* __restrict__ gt1, u16* __restrict__ gt2,
                           u16* __restrict__ cw1, u16* __restrict__ cw2,
                           u16* __restrict__ f11, u16* __restrict__ f12,
                           float* __restrict__ seq) {
    int idx = blockIdx.x * 256 + threadIdx.x;
    if (idx < 65536) {
        int mc = idx >> 9, r = idx & 511, m = mc & 63;
        int p = (m * r) & 511;
        float a = (float)p * (1.0f / 256.0f);
        float c = cospif(a), s = sinpif(a);
        float Fv = (mc < 64) ? c : -s;
        float cm = (m == 0) ? (1.0f / 512.0f) : (2.0f / 512.0f);
        float Gv = (mc < 64) ? cm * c : ((m == 0) ? 0.0f : -cm * s);
        f1[idx] = f2bf_hi(Fv); f2[idx] = f2bf_lo(Fv);
        size_t g = (size_t)r * 128 + mc;
        gt1[g] = f2bf_hi(Gv); gt2[g] = f2bf_lo(Gv);
    } else if (idx < 131072) {
        int i = idx - 65536;
        float v = conv_w[i];
        cw1[i] = f2bf_hi(v); cw2[i] = f2bf_lo(v);
    } else if (idx < 163840) {
        int i = idx - 131072;          // j*128 + c
        int j = i >> 7, c = i & 127;
        float v = fc1_w[(size_t)c * 256 + j];
        f11[i] = f2bf_hi(v); f12[i] = f2bf_lo(v);
    } else {
        int i = idx - 163840;          // < 32*24*512
        int b = i / (NTH * NR);
        int rem = i - b * (NTH * NR);
        seq[(size_t)b * SEQROWS * NR + rem] = z[i];
    }
}

// spec_w (l,i,o,m) -> planes [l][m][o][i] hi/lo, coalesced both directions.
__global__ __launch_bounds__(256) void prep_specw(const float* __restrict__ wr, const float* __restrict__ wi,
                           u16* __restrict__ wr1, u16* __restrict__ wr2,
                           u16* __restrict__ wi1, u16* __restrict__ wi2) {
    __shared__ float tile[128][65];
    int l = blockIdx.x >> 7, o = blockIdx.x & 127;
    int tid = threadIdx.x;
    size_t sbase = (size_t)l * 1048576 + (size_t)o * 64;
    size_t dbase = (size_t)l * 64 * 16384 + (size_t)o * 128;
    for (int pass = 0; pass < 2; pass++) {
        const float* src = pass ? wi : wr;
        u16* d1 = pass ? wi1 : wr1;
        u16* d2 = pass ? wi2 : wr2;
        if (pass) __syncthreads();
        for (int e = tid; e < 8192; e += 256) {
            int i = e >> 6, m = e & 63;
            tile[i][m] = src[sbase + (size_t)i * 8192 + m];
        }
        __syncthreads();
        for (int e = tid; e < 4096; e += 256) {
            int m = e >> 6, i2 = (e & 63) * 2;
            float v0 = tile[i2][m], v1 = tile[i2 + 1][m];
            u32 hh = (u32)f2bf_hi(v0) | ((u32)f2bf_hi(v1) << 16);
            u32 ll = (u32)f2bf_lo(v0) | ((u32)f2bf_lo(v1) << 16);
            size_t d = dbase + (size_t)m * 16384 + i2;
            *(u32*)&d1[d] = hh;
            *(u32*)&d2[d] = ll;
        }
    }
}

// ---------------------------------------------------------------------------
// fc0 (fp32), step 0 only: writes ht[b][r][c] AND htc[b][c][r] planes.
// ---------------------------------------------------------------------------
__global__ __launch_bounds__(256) void fc0_kernel(const float* __restrict__ seq,
        const float* __restrict__ t_grid, const float* __restrict__ fc0_w,
        const float* __restrict__ fc0_b, u16* __restrict__ ht1, u16* __restrict__ ht2,
        u16* __restrict__ htc1, u16* __restrict__ htc2, int step) {
    __shared__ float wlds[28 * 128];
    __shared__ float blds[128];
    int b = blockIdx.y, rblk = blockIdx.x;
    int tid = threadIdx.x;
    for (int t = tid; t < 28 * 128; t += 256) wlds[t] = fc0_w[t];
    if (tid < 128) blds[tid] = fc0_b[tid];
    __syncthreads();
    int lane = tid & 63, wq = tid >> 6;
    int r = rblk * 64 + lane;
    float sv[24];
    const float* sp = seq + ((size_t)b * SEQROWS + step) * NR + r;
#pragma unroll
    for (int t = 0; t < 24; t++) sv[t] = sp[(size_t)t * NR];
    float tt = t_grid[b * 24 + 23] + (float)(step + 1);
    float ang24 = 6.28318530717958647692f * tt * (1.0f / 24.0f);
    float ang168 = 6.28318530717958647692f * tt * (1.0f / 168.0f);
    float s24 = sinf(ang24), c24 = cosf(ang24), s168 = sinf(ang168);
    float xc = (float)r * (1.0f / 511.0f);
    size_t rowoff = ((size_t)b * NR + r) * NW;
#pragma unroll 2
    for (int w0 = 0; w0 < 32; w0 += 2) {
        float acc2[2];
#pragma unroll
        for (int q = 0; q < 2; q++) {
            int w = wq * 32 + w0 + q;
            float acc = blds[w];
#pragma unroll
            for (int t = 0; t < 24; t++) acc += sv[t] * wlds[t * 128 + w];
            acc += s24 * wlds[24 * 128 + w] + c24 * wlds[25 * 128 + w]
                 + s168 * wlds[26 * 128 + w] + xc * wlds[27 * 128 + w];
            acc2[q] = acc;
        }
        u16 h0 = f2bf_hi(acc2[0]), h1 = f2bf_hi(acc2[1]);
        u16 l0 = f2bf_lo(acc2[0]), l1 = f2bf_lo(acc2[1]);
        size_t off = rowoff + wq * 32 + w0;
        *(u32*)&ht1[off] = (u32)h0 | ((u32)h1 << 16);
        *(u32*)&ht2[off] = (u32)l0 | ((u32)l1 << 16);
        int w = wq * 32 + w0;
        size_t coff = ((size_t)b * 128 + w) * 512 + r;
        htc1[coff] = h0; htc1[coff + 512] = h1;
        htc2[coff] = l0; htc2[coff + 512] = l1;
    }
}

// ---------------------------------------------------------------------------
// dft (MFMA): X[128][4096] = F * htc^T, K=512, BK=64, depth-3 pipelined.
// grid (128 n-tiles of 32, 4 mc-tiles) = 512 blocks (2/CU).
// ---------------------------------------------------------------------------
__global__ __launch_bounds__(256) void dft_mfma(const u16* __restrict__ f1, const u16* __restrict__ f2,
        const u16* __restrict__ htc1, const u16* __restrict__ htc2,
        u16* __restrict__ x1, u16* __restrict__ x2) {
    __shared__ __align__(16) u16 A1[2][32 * 72], A2[2][32 * 72];
    __shared__ __align__(16) u16 B1[2][32 * 72], B2[2][32 * 72];
    int bx = blockIdx.x;
    int mct = blockIdx.y * 32;
    int tid = threadIdx.x, wid = tid >> 6, l = tid & 63;
    int wm0 = (wid >> 1) * 16, wn0 = (wid & 1) * 16;
    int arow = l & 15, kgrp = (l >> 4) * 8;
    f32x4 acc = {0.f, 0.f, 0.f, 0.f};
    int pl = tid >> 7, row = (tid >> 2) & 31, sp = (tid & 3) * 16;
    const u16* asrc = (pl ? f2 : f1) + (size_t)(mct + row) * 512 + sp;
    const u16* bsrc = (pl ? htc2 : htc1)
                      + ((size_t)(bx >> 2) * 128 + (bx & 3) * 32 + row) * 512 + sp;
    int loff = row * 72 + sp;
    u16* ad0 = (pl ? A2[0] : A1[0]) + loff;  u16* ad1 = (pl ? A2[1] : A1[1]) + loff;
    u16* bd0 = (pl ? B2[0] : B1[0]) + loff;  u16* bd1 = (pl ? B2[1] : B1[1]) + loff;
    uint4 oA0, oA1, oB0, oB1, eA0, eA1, eB0, eB1;
    oA0 = *(const uint4*)(asrc);     oA1 = *(const uint4*)(asrc + 8);
    oB0 = *(const uint4*)(bsrc);     oB1 = *(const uint4*)(bsrc + 8);
    *(uint4*)ad0 = oA0; *(uint4*)(ad0 + 8) = oA1;
    *(uint4*)bd0 = oB0; *(uint4*)(bd0 + 8) = oB1;
    oA0 = *(const uint4*)(asrc + 64);  oA1 = *(const uint4*)(asrc + 72);
    oB0 = *(const uint4*)(bsrc + 64);  oB1 = *(const uint4*)(bsrc + 72);
    eA0 = *(const uint4*)(asrc + 128); eA1 = *(const uint4*)(asrc + 136);
    eB0 = *(const uint4*)(bsrc + 128); eB1 = *(const uint4*)(bsrc + 136);
    __syncthreads();
#define DFT_COMPUTE(BUF)                                                       \
    { _Pragma("unroll")                                                        \
      for (int kk = 0; kk < 64; kk += 32) {                                    \
        bf16x8 a1 = *(const bf16x8*)&A1[BUF][(wm0 + arow) * 72 + kk + kgrp];   \
        bf16x8 a2 = *(const bf16x8*)&A2[BUF][(wm0 + arow) * 72 + kk + kgrp];   \
        bf16x8 b1 = *(const bf16x8*)&B1[BUF][(wn0 + arow) * 72 + kk + kgrp];   \
        bf16x8 b2 = *(const bf16x8*)&B2[BUF][(wn0 + arow) * 72 + kk + kgrp];   \
        acc = MFMA16(a1, b1, acc);                                             \
        acc = MFMA16(a1, b2, acc);                                             \
        acc = MFMA16(a2, b1, acc);                                             \
      } }
    for (int k = 0; k < 8; k += 2) {
        DFT_COMPUTE(0)
        *(uint4*)ad1 = oA0; *(uint4*)(ad1 + 8) = oA1;
        *(uint4*)bd1 = oB0; *(uint4*)(bd1 + 8) = oB1;
        if (k < 5) {
            int ko = (k + 3) * 64;
            oA0 = *(const uint4*)(asrc + ko);      oA1 = *(const uint4*)(asrc + ko + 8);
            oB0 = *(const uint4*)(bsrc + ko);      oB1 = *(const uint4*)(bsrc + ko + 8);
        }
        __syncthreads();
        DFT_COMPUTE(1)
        if (k < 6) {
            *(uint4*)ad0 = eA0; *(uint4*)(ad0 + 8) = eA1;
            *(uint4*)bd0 = eB0; *(uint4*)(bd0 + 8) = eB1;
            if (k < 4) {
                int ko = (k + 4) * 64;
                eA0 = *(const uint4*)(asrc + ko);  eA1 = *(const uint4*)(asrc + ko + 8);
                eB0 = *(const uint4*)(bsrc + ko);  eB1 = *(const uint4*)(bsrc + ko + 8);
            }
        }
        __syncthreads();
    }
#undef DFT_COMPUTE
    int mcr = mct + wm0 + (l >> 4) * 4;
    int n0 = bx * 32 + wn0 + (l & 15);
#pragma unroll
    for (int j = 0; j < 4; j++) {
        size_t o0 = (size_t)(mcr + j) * 4096 + n0;
        x1[o0] = f2bf_hi(acc[j]); x2[o0] = f2bf_lo(acc[j]);
    }
}

// ---------------------------------------------------------------------------
// modemix (MFMA, single-barrier): Y = W *c X per mode, K=128 fully in LDS.
// grid (64 m, 4 oq), 256 thr.
// ---------------------------------------------------------------------------
__global__ __launch_bounds__(256) void modemix_mfma(const u16* __restrict__ x1, const u16* __restrict__ x2,
        const u16* __restrict__ wr1, const u16* __restrict__ wr2,
        const u16* __restrict__ wi1, const u16* __restrict__ wi2,
        u16* __restrict__ y1, u16* __restrict__ y2, int layer) {
    __shared__ __align__(16) u16 POOL[8 * 32 * 136];
    int m = blockIdx.x, oq = blockIdx.y;
    int tid = threadIdx.x, wid = tid >> 6, l = tid & 63;
    int wo0 = (wid >> 1) * 16, wb0 = (wid & 1) * 16;
    int arow = l & 15, kgrp = (l >> 4) * 8;
    size_t wbase = (((size_t)layer * 64 + m) * 128 + oq * 32) * 128;
#pragma unroll
    for (int q = 0; q < 16; q++) {
        const int slab = q >> 1;
        int rr = ((q & 1) << 4) + (tid >> 4);
        int seg = tid & 15;
        const u16* src;
        if      (slab == 0) src = wr1 + wbase + (size_t)rr * 128 + seg * 8;
        else if (slab == 1) src = wr2 + wbase + (size_t)rr * 128 + seg * 8;
        else if (slab == 2) src = wi1 + wbase + (size_t)rr * 128 + seg * 8;
        else if (slab == 3) src = wi2 + wbase + (size_t)rr * 128 + seg * 8;
        else if (slab == 4) src = x1 + (size_t)m * 4096 + rr * 128 + seg * 8;
        else if (slab == 5) src = x2 + (size_t)m * 4096 + rr * 128 + seg * 8;
        else if (slab == 6) src = x1 + (size_t)(64 + m) * 4096 + rr * 128 + seg * 8;
        else                src = x2 + (size_t)(64 + m) * 4096 + rr * 128 + seg * 8;
        *(uint4*)&POOL[slab * 4352 + rr * 136 + seg * 8] = *(const uint4*)src;
    }
    __syncthreads();
    f32x4 ar = {0.f, 0.f, 0.f, 0.f}, ai = {0.f, 0.f, 0.f, 0.f};
    int aoB = (wo0 + arow) * 136 + kgrp;
    int boB = (wb0 + arow) * 136 + kgrp;
#pragma unroll
    for (int kg = 0; kg < 4; kg++) {
        int ao = aoB + kg * 32;
        int bo = boB + kg * 32;
        bf16x8 Wr1 = *(const bf16x8*)&POOL[0 * 4352 + ao];
        bf16x8 Wr2 = *(const bf16x8*)&POOL[1 * 4352 + ao];
        bf16x8 Wi1 = *(const bf16x8*)&POOL[2 * 4352 + ao];
        bf16x8 Wi2 = *(const bf16x8*)&POOL[3 * 4352 + ao];
        bf16x8 Xr1 = *(const bf16x8*)&POOL[4 * 4352 + bo];
        bf16x8 Xr2 = *(const bf16x8*)&POOL[5 * 4352 + bo];
        bf16x8 Xi1 = *(const bf16x8*)&POOL[6 * 4352 + bo];
        bf16x8 Xi2 = *(const bf16x8*)&POOL[7 * 4352 + bo];
        bf16x8 nWi1 = negbf(Wi1), nWi2 = negbf(Wi2);
        ar = MFMA16(Wr1, Xr1, ar); ar = MFMA16(Wr1, Xr2, ar); ar = MFMA16(Wr2, Xr1, ar);
        ar = MFMA16(nWi1, Xi1, ar); ar = MFMA16(nWi1, Xi2, ar); ar = MFMA16(nWi2, Xi1, ar);
        ai = MFMA16(Wi1, Xr1, ai); ai = MFMA16(Wi1, Xr2, ai); ai = MFMA16(Wi2, Xr1, ai);
        ai = MFMA16(Wr1, Xi1, ai); ai = MFMA16(Wr1, Xi2, ai); ai = MFMA16(Wr2, Xi1, ai);
    }
    int ob = oq * 32 + wo0 + (l >> 4) * 4;
    int bb = wb0 + (l & 15);
#pragma unroll
    for (int j = 0; j < 4; j++) {
        size_t o = ((size_t)bb * 128 + ob + j) * 128;
        y1[o + m] = f2bf_hi(ar[j]); y2[o + m] = f2bf_lo(ar[j]);
        y1[o + 64 + m] = f2bf_hi(ai[j]); y2[o + 64 + m] = f2bf_lo(ai[j]);
    }
}

// ---------------------------------------------------------------------------
// idft+conv (layers 0..2): C[o][r] = [Y|CW](o,256)*[GT;ht](256,r)+bias,GELU.
// grid (8 rt, 2 ot, 32 b). T-transpose epilogue writes htc.
// ---------------------------------------------------------------------------
__global__ __launch_bounds__(256) void idft_conv_mfma(const u16* __restrict__ y1, const u16* __restrict__ y2,
        const u16* __restrict__ gt1, const u16* __restrict__ gt2,
        const u16* __restrict__ hc1, const u16* __restrict__ hc2,
        const u16* __restrict__ cw1, const u16* __restrict__ cw2,
        const float* __restrict__ conv_b,
        u16* __restrict__ hn1, u16* __restrict__ hn2,
        u16* __restrict__ htc1, u16* __restrict__ htc2, int layer) {
    __shared__ __align__(16) u16 A1[2][2560], A2[2][2560];
    __shared__ __align__(16) u16 B1[2][2560], B2[2][2560];
    __shared__ __align__(16) u16 T1[64 * 66], T2[64 * 66];
    int rt = blockIdx.x * 64, ot = blockIdx.y * 64, b = blockIdx.z;
    int tid = threadIdx.x, wid = tid >> 6, l = tid & 63;
    int wo0 = (wid >> 1) * 32, wr0 = (wid & 1) * 32;
    int arow = (l & 15), kgrp = (l >> 4) * 8;
    int srow = (tid >> 2) & 63, sseg = tid & 3;
    int soff = srow * 40 + sseg * 8;
    const u16* ya = y1 + ((size_t)b * 128 + ot + srow) * 128 + sseg * 8;
    const u16* yb = y2 + ((size_t)b * 128 + ot + srow) * 128 + sseg * 8;
    const u16* ca = cw1 + ((size_t)layer * 128 + ot + srow) * 128 + sseg * 8;
    const u16* cb = cw2 + ((size_t)layer * 128 + ot + srow) * 128 + sseg * 8;
    const u16* ga = gt1 + (size_t)(rt + srow) * 128 + sseg * 8;
    const u16* gb = gt2 + (size_t)(rt + srow) * 128 + sseg * 8;
    const u16* ha = hc1 + ((size_t)b * 512 + rt + srow) * 128 + sseg * 8;
    const u16* hb = hc2 + ((size_t)b * 512 + rt + srow) * 128 + sseg * 8;
    f32x4 acc[2][2] = {{{0.f,0.f,0.f,0.f},{0.f,0.f,0.f,0.f}},{{0.f,0.f,0.f,0.f},{0.f,0.f,0.f,0.f}}};
    uint4 raO0, raO1, rbO0, rbO1, raE0, raE1, rbE0, rbE1;
#define ILOAD(chk, Ra0, Ra1, Rb0, Rb1)                                        \
    {   int k0_ = ((chk) & 3) * 32;                                           \
        if ((chk) < 4) {                                                      \
            Ra0 = *(const uint4*)(ya + k0_); Ra1 = *(const uint4*)(yb + k0_); \
            Rb0 = *(const uint4*)(ga + k0_); Rb1 = *(const uint4*)(gb + k0_); \
        } else {                                                              \
            Ra0 = *(const uint4*)(ca + k0_); Ra1 = *(const uint4*)(cb + k0_); \
            Rb0 = *(const uint4*)(ha + k0_); Rb1 = *(const uint4*)(hb + k0_); \
        } }
#define ISTORE(BUF, Ra0, Ra1, Rb0, Rb1)                                      \
    {   *(uint4*)(A1[BUF] + soff) = Ra0; *(uint4*)(A2[BUF] + soff) = Ra1;     \
        *(uint4*)(B1[BUF] + soff) = Rb0; *(uint4*)(B2[BUF] + soff) = Rb1; }
#define ICOMP(BUF)                                                            \
    {   bf16x8 bfr[2][2];                                                     \
        _Pragma("unroll")                                                     \
        for (int rf = 0; rf < 2; rf++) {                                      \
            bfr[rf][0] = *(const bf16x8*)&B1[BUF][(wr0 + rf * 16 + arow) * 40 + kgrp]; \
            bfr[rf][1] = *(const bf16x8*)&B2[BUF][(wr0 + rf * 16 + arow) * 40 + kgrp]; \
        }                                                                     \
        _Pragma("unroll")                                                     \
        for (int of = 0; of < 2; of++) {                                      \
            bf16x8 a1 = *(const bf16x8*)&A1[BUF][(wo0 + of * 16 + arow) * 40 + kgrp]; \
            bf16x8 a2 = *(const bf16x8*)&A2[BUF][(wo0 + of * 16 + arow) * 40 + kgrp]; \
            _Pragma("unroll")                                                 \
            for (int rf = 0; rf < 2; rf++) {                                  \
                acc[of][rf] = MFMA16(a1, bfr[rf][0], acc[of][rf]);            \
                acc[of][rf] = MFMA16(a1, bfr[rf][1], acc[of][rf]);            \
                acc[of][rf] = MFMA16(a2, bfr[rf][0], acc[of][rf]);            \
            }                                                                 \
        } }
    ILOAD(0, raO0, raO1, rbO0, rbO1)
    ISTORE(0, raO0, raO1, rbO0, rbO1)
    ILOAD(1, raO0, raO1, rbO0, rbO1)
    ILOAD(2, raE0, raE1, rbE0, rbE1)
    __syncthreads();
    for (int k = 0; k < 8; k += 2) {
        ICOMP(0)
        ISTORE(1, raO0, raO1, rbO0, rbO1)
        if (k < 5) ILOAD(k + 3, raO0, raO1, rbO0, rbO1)
        __syncthreads();
        ICOMP(1)
        if (k < 6) {
            ISTORE(0, raE0, raE1, rbE0, rbE1)
            if (k < 4) ILOAD(k + 4, raE0, raE1, rbE0, rbE1)
        }
        __syncthreads();
    }
#undef ILOAD
#undef ISTORE
#undef ICOMP
#pragma unroll
    for (int of = 0; of < 2; of++) {
        int obl = wo0 + of * 16 + (l >> 4) * 4;
        int ob = ot + obl;
#pragma unroll
        for (int rf = 0; rf < 2; rf++) {
            int rloc = wr0 + rf * 16 + (l & 15);
            int r = rt + rloc;
            float v0 = gelu_exact(acc[of][rf][0] + conv_b[layer * 128 + ob + 0]);
            float v1 = gelu_exact(acc[of][rf][1] + conv_b[layer * 128 + ob + 1]);
            float v2 = gelu_exact(acc[of][rf][2] + conv_b[layer * 128 + ob + 2]);
            float v3 = gelu_exact(acc[of][rf][3] + conv_b[layer * 128 + ob + 3]);
            ushort4 hv, lv;
            hv.x = f2bf_hi(v0); hv.y = f2bf_hi(v1); hv.z = f2bf_hi(v2); hv.w = f2bf_hi(v3);
            lv.x = f2bf_lo(v0); lv.y = f2bf_lo(v1); lv.z = f2bf_lo(v2); lv.w = f2bf_lo(v3);
            size_t off = ((size_t)b * 512 + r) * 128 + ob;
            *(ushort4*)&hn1[off] = hv;
            *(ushort4*)&hn2[off] = lv;
            T1[(obl + 0) * 66 + rloc] = hv.x; T1[(obl + 1) * 66 + rloc] = hv.y;
            T1[(obl + 2) * 66 + rloc] = hv.z; T1[(obl + 3) * 66 + rloc] = hv.w;
            T2[(obl + 0) * 66 + rloc] = lv.x; T2[(obl + 1) * 66 + rloc] = lv.y;
            T2[(obl + 2) * 66 + rloc] = lv.z; T2[(obl + 3) * 66 + rloc] = lv.w;
        }
    }
    __syncthreads();
#pragma unroll
    for (int q = 0; q < 8; q++) {
        int t = tid + q * 256;
        int o = t >> 5, ru = t & 31;
        u32 vh = *(const u32*)&T1[o * 66 + ru * 2];
        u32 vl = *(const u32*)&T2[o * 66 + ru * 2];
        size_t off = ((size_t)b * 128 + ot + o) * 512 + rt + ru * 2;
        *(u32*)&htc1[off] = vh;
        *(u32*)&htc2[off] = vl;
    }
}

// ---------------------------------------------------------------------------
// Layer-3 fused: idft+conv (all 128 o per block) -> h tile in LDS -> head
// (fc1 GEMM in two j-halves + gelu + fc2 reduce + z update) -> fc0 for next
// step. grid (8 rt, 32 b) = 256 blocks. Bit-identical j/k accumulation order.
// ---------------------------------------------------------------------------
__global__ __launch_bounds__(256) void idft_head_mfma(
        const u16* __restrict__ y1, const u16* __restrict__ y2,
        const u16* __restrict__ gt1, const u16* __restrict__ gt2,
        const u16* __restrict__ hc1, const u16* __restrict__ hc2,
        const u16* __restrict__ cw1, const u16* __restrict__ cw2,
        const float* __restrict__ conv_b,
        const u16* __restrict__ f11, const u16* __restrict__ f12,
        const float* __restrict__ fc1_b, const float* __restrict__ fc2_w,
        const float* __restrict__ fc2_b,
        const float* __restrict__ t_grid, const float* __restrict__ fc0_w,
        const float* __restrict__ fc0_b,
        float* __restrict__ seq, float* __restrict__ preds,
        u16* __restrict__ nht1, u16* __restrict__ nht2,
        u16* __restrict__ nhtc1, u16* __restrict__ nhtc2,
        int layer, int step, int do_fc0) {
    __shared__ __align__(16) u16 POOL[35072];   // 70144 B
    int rt = blockIdx.x * 64, b = blockIdx.y;
    int tid = threadIdx.x, wid = tid >> 6, l = tid & 63;
    int wo0 = (wid >> 1) * 32, wr0 = (wid & 1) * 32;
    int arow = (l & 15), kgrp = (l >> 4) * 8;
    u16* A1 = POOL;                  // [2][5120]
    u16* A2 = POOL + 10240;
    u16* B1 = POOL + 20480;          // [2][2560]
    u16* B2 = POOL + 25600;
    int srow = tid >> 2, sseg = tid & 3;
    const u16* ya0 = y1 + ((size_t)b * 128 + srow) * 128 + sseg * 8;
    const u16* ya1 = ya0 + 64 * 128;
    const u16* yb0 = y2 + ((size_t)b * 128 + srow) * 128 + sseg * 8;
    const u16* yb1 = yb0 + 64 * 128;
    const u16* ca0 = cw1 + ((size_t)layer * 128 + srow) * 128 + sseg * 8;
    const u16* ca1 = ca0 + 64 * 128;
    const u16* cb0 = cw2 + ((size_t)layer * 128 + srow) * 128 + sseg * 8;
    const u16* cb1 = cb0 + 64 * 128;
    const u16* ga = gt1 + (size_t)(rt + srow) * 128 + sseg * 8;
    const u16* gb = gt2 + (size_t)(rt + srow) * 128 + sseg * 8;
    const u16* ha = hc1 + ((size_t)b * 512 + rt + srow) * 128 + sseg * 8;
    const u16* hb = hc2 + ((size_t)b * 512 + rt + srow) * 128 + sseg * 8;
    int soffA0 = srow * 40 + sseg * 8;
    int soffA1 = (srow + 64) * 40 + sseg * 8;
    f32x4 acc[2][2][2];
#pragma unroll
    for (int ot = 0; ot < 2; ot++)
#pragma unroll
        for (int of = 0; of < 2; of++)
#pragma unroll
            for (int rf = 0; rf < 2; rf++) acc[ot][of][rf] = (f32x4){0.f, 0.f, 0.f, 0.f};
    uint4 oA0, oA1r, oA2r, oA3, oB0, oB1;
    uint4 eA0, eA1r, eA2r, eA3, eB0, eB1;
#define ILOAD(chk, Q0, Q1, Q2, Q3, R0, R1)                                    \
    {   int k0_ = ((chk) & 3) * 32;                                           \
        if ((chk) < 4) {                                                      \
            Q0 = *(const uint4*)(ya0 + k0_); Q1 = *(const uint4*)(ya1 + k0_); \
            Q2 = *(const uint4*)(yb0 + k0_); Q3 = *(const uint4*)(yb1 + k0_); \
            R0 = *(const uint4*)(ga + k0_);  R1 = *(const uint4*)(gb + k0_);  \
        } else {                                                              \
            Q0 = *(const uint4*)(ca0 + k0_); Q1 = *(const uint4*)(ca1 + k0_); \
            Q2 = *(const uint4*)(cb0 + k0_); Q3 = *(const uint4*)(cb1 + k0_); \
            R0 = *(const uint4*)(ha + k0_);  R1 = *(const uint4*)(hb + k0_);  \
        } }
#define ISTORE(BUF, Q0, Q1, Q2, Q3, R0, R1)                                   \
    {   *(uint4*)(A1 + (BUF) * 5120 + soffA0) = Q0;                           \
        *(uint4*)(A1 + (BUF) * 5120 + soffA1) = Q1;                           \
        *(uint4*)(A2 + (BUF) * 5120 + soffA0) = Q2;                           \
        *(uint4*)(A2 + (BUF) * 5120 + soffA1) = Q3;                           \
        *(uint4*)(B1 + (BUF) * 2560 + soffA0) = R0;                           \
        *(uint4*)(B2 + (BUF) * 2560 + soffA0) = R1; }
#define ICOMP(BUF)                                                            \
    {   bf16x8 bfr[2][2];                                                     \
        _Pragma("unroll")                                                     \
        for (int rf = 0; rf < 2; rf++) {                                      \
            bfr[rf][0] = *(const bf16x8*)&B1[(BUF) * 2560 + (wr0 + rf * 16 + arow) * 40 + kgrp]; \
            bfr[rf][1] = *(const bf16x8*)&B2[(BUF) * 2560 + (wr0 + rf * 16 + arow) * 40 + kgrp]; \
        }                                                                     \
        _Pragma("unroll")                                                     \
        for (int ot = 0; ot < 2; ot++) {                                      \
        _Pragma("unroll")                                                     \
        for (int of = 0; of < 2; of++) {                                      \
            bf16x8 a1v = *(const bf16x8*)&A1[(BUF) * 5120 + (ot * 64 + wo0 + of * 16 + arow) * 40 + kgrp]; \
            bf16x8 a2v = *(const bf16x8*)&A2[(BUF) * 5120 + (ot * 64 + wo0 + of * 16 + arow) * 40 + kgrp]; \
            _Pragma("unroll")                                                 \
            for (int rf = 0; rf < 2; rf++) {                                  \
                acc[ot][of][rf] = MFMA16(a1v, bfr[rf][0], acc[ot][of][rf]);   \
                acc[ot][of][rf] = MFMA16(a1v, bfr[rf][1], acc[ot][of][rf]);   \
                acc[ot][of][rf] = MFMA16(a2v, bfr[rf][0], acc[ot][of][rf]);   \
            }                                                                 \
        } } }
    ILOAD(0, oA0, oA1r, oA2r, oA3, oB0, oB1)
    ISTORE(0, oA0, oA1r, oA2r, oA3, oB0, oB1)
    ILOAD(1, oA0, oA1r, oA2r, oA3, oB0, oB1)
    ILOAD(2, eA0, eA1r, eA2r, eA3, eB0, eB1)
    __syncthreads();
    for (int k = 0; k < 8; k += 2) {
        ICOMP(0)
        ISTORE(1, oA0, oA1r, oA2r, oA3, oB0, oB1)
        if (k < 5) ILOAD(k + 3, oA0, oA1r, oA2r, oA3, oB0, oB1)
        __syncthreads();
        ICOMP(1)
        if (k < 6) {
            ISTORE(0, eA0, eA1r, eA2r, eA3, eB0, eB1)
            if (k < 4) ILOAD(k + 4, eA0, eA1r, eA2r, eA3, eB0, eB1)
        }
        __syncthreads();
    }
#undef ILOAD
#undef ISTORE
#undef ICOMP
    __syncthreads();                 // A/B reads done; alias h over POOL
    u16* h1 = POOL;                  // [64][136] hi
    u16* h2 = POOL + 8704;           // [64][136] lo
#pragma unroll
    for (int ot = 0; ot < 2; ot++) {
#pragma unroll
        for (int of = 0; of < 2; of++) {
            int obl = ot * 64 + wo0 + of * 16 + (l >> 4) * 4;
#pragma unroll
            for (int rf = 0; rf < 2; rf++) {
                int rloc = wr0 + rf * 16 + (l & 15);
                float v0 = gelu_exact(acc[ot][of][rf][0] + conv_b[layer * 128 + obl + 0]);
                float v1 = gelu_exact(acc[ot][of][rf][1] + conv_b[layer * 128 + obl + 1]);
                float v2 = gelu_exact(acc[ot][of][rf][2] + conv_b[layer * 128 + obl + 2]);
                float v3 = gelu_exact(acc[ot][of][rf][3] + conv_b[layer * 128 + obl + 3]);
                ushort4 hv, lv;
                hv.x = f2bf_hi(v0); hv.y = f2bf_hi(v1); hv.z = f2bf_hi(v2); hv.w = f2bf_hi(v3);
                lv.x = f2bf_lo(v0); lv.y = f2bf_lo(v1); lv.z = f2bf_lo(v2); lv.w = f2bf_lo(v3);
                *(ushort4*)&h1[rloc * 136 + obl] = hv;
                *(ushort4*)&h2[rloc * 136 + obl] = lv;
            }
        }
    }
    // ---- head: D[j][r] = fc1t(j,c)*h(r,c); dx = sum_j gelu(D+b1)*w2 ----
    u16* HA1 = POOL + 17408;         // [128][40]
    u16* HA2 = POOL + 22528;
    float* fc2s = (float*)(POOL + 27648);    // 256 f
    float* fc1bs = (float*)(POOL + 28160);   // 256 f
    fc2s[tid] = fc2_w[tid];
    fc1bs[tid] = fc1_b[tid];
    float dx = 0.0f;
    for (int jh = 0; jh < 2; jh++) {
        f32x4 hacc[8];
#pragma unroll
        for (int jf = 0; jf < 8; jf++) hacc[jf] = (f32x4){0.f, 0.f, 0.f, 0.f};
        for (int k0 = 0; k0 < 128; k0 += 32) {
            __syncthreads();
#pragma unroll
            for (int q = 0; q < 4; q++) {
                int t = tid + q * 256;
                int pl = t >> 9, j = (t >> 2) & 127, seg = t & 3;
                const u16* src = (pl ? f12 : f11) + (size_t)(jh * 128 + j) * 128 + k0 + seg * 8;
                *(uint4*)((pl ? HA2 : HA1) + j * 40 + seg * 8) = *(const uint4*)src;
            }
            __syncthreads();
            int bo = (wid * 16 + arow) * 136 + k0 + kgrp;
            bf16x8 hb1 = *(const bf16x8*)&h1[bo];
            bf16x8 hb2 = *(const bf16x8*)&h2[bo];
#pragma unroll
            for (int jf = 0; jf < 8; jf++) {
                int ao = (jf * 16 + arow) * 40 + kgrp;
                bf16x8 a1 = *(const bf16x8*)&HA1[ao];
                bf16x8 a2 = *(const bf16x8*)&HA2[ao];
                hacc[jf] = MFMA16(a1, hb1, hacc[jf]);
                hacc[jf] = MFMA16(a1, hb2, hacc[jf]);
                hacc[jf] = MFMA16(a2, hb1, hacc[jf]);
            }
        }
#pragma unroll
        for (int jf = 0; jf < 8; jf++) {
            int jbase = jh * 128 + jf * 16 + (l >> 4) * 4;
#pragma unroll
            for (int jj = 0; jj < 4; jj++) {
                dx += gelu_exact(hacc[jf][jj] + fc1bs[jbase + jj]) * fc2s[jbase + jj];
            }
        }
    }
    dx += __shfl_xor(dx, 16);
    dx += __shfl_xor(dx, 32);
    bool zlane = ((l >> 4) == 0);
    int rml = wid * 16 + arow;
    float zn = 0.0f;
    if (zlane) {
        int r = rt + rml;
        zn = seq[((size_t)b * SEQROWS + step + 23) * NR + r] + dx + fc2_b[0];
        seq[((size_t)b * SEQROWS + step + 24) * NR + r] = zn;
        preds[((size_t)b * NSTEPS + step) * NR + r] = zn;
    }
    if (do_fc0) {
        float* win = (float*)POOL;                 // [24][64]
        float* wl  = (float*)POOL + 2048;          // [28][128]
        float* bl  = (float*)POOL + 2048 + 3584;   // [128]
        __syncthreads();   // all h/HA LDS reads done before aliasing
        for (int t = tid; t < 23 * 64; t += 256) {
            int tr = t >> 6, c = t & 63;
            win[tr * 64 + c] = seq[((size_t)b * SEQROWS + step + 1 + tr) * NR + rt + c];
        }
        for (int t = tid; t < 28 * 128; t += 256) wl[t] = fc0_w[t];
        if (tid < 128) bl[tid] = fc0_b[tid];
        if (zlane) win[23 * 64 + rml] = zn;
        __syncthreads();
        int lane = tid & 63, wq = tid >> 6;
        int r = rt + lane;
        float sv[24];
#pragma unroll
        for (int t = 0; t < 24; t++) sv[t] = win[t * 64 + lane];
        float tt = t_grid[b * 24 + 23] + (float)(step + 2);
        float ang24 = 6.28318530717958647692f * tt * (1.0f / 24.0f);
        float ang168 = 6.28318530717958647692f * tt * (1.0f / 168.0f);
        float s24 = sinf(ang24), c24 = cosf(ang24), s168 = sinf(ang168);
        float xc = (float)r * (1.0f / 511.0f);
        size_t rowoff = ((size_t)b * NR + r) * NW;
#pragma unroll 2
        for (int w0 = 0; w0 < 32; w0 += 2) {
            float acc2[2];
#pragma unroll
            for (int q = 0; q < 2; q++) {
                int w = wq * 32 + w0 + q;
                float a = bl[w];
#pragma unroll
                for (int t = 0; t < 24; t++) a += sv[t] * wl[t * 128 + w];
                a += s24 * wl[24 * 128 + w] + c24 * wl[25 * 128 + w]
                   + s168 * wl[26 * 128 + w] + xc * wl[27 * 128 + w];
                acc2[q] = a;
            }
            u16 h0 = f2bf_hi(acc2[0]), h1v = f2bf_hi(acc2[1]);
            u16 l0 = f2bf_lo(acc2[0]), l1v = f2bf_lo(acc2[1]);
            size_t off = rowoff + wq * 32 + w0;
            *(u32*)&nht1[off] = (u32)h0 | ((u32)h1v << 16);
            *(u32*)&nht2[off] = (u32)l0 | ((u32)l1v << 16);
            int w = wq * 32 + w0;
            size_t coff = ((size_t)b * 128 + w) * 512 + r;
            nhtc1[coff] = h0; nhtc1[coff + 512] = h1v;
            nhtc2[coff] = l0; nhtc2[coff + 512] = l1v;
        }
    }
}

// ---------------------------------------------------------------------------
extern "C" void kernel_launch(void* const* d_in, const int* in_sizes, int n_in,
                              void* d_out, int out_size, void* d_ws, size_t ws_size,
                              hipStream_t stream) {
    (void)in_sizes; (void)n_in; (void)out_size; (void)ws_size;
    const float* z       = (const float*)d_in[0];
    const float* t_grid  = (const float*)d_in[1];
    const float* fc0_w   = (const float*)d_in[2];
    const float* fc0_b   = (const float*)d_in[3];
    const float* spec_wr = (const float*)d_in[4];
    const float* spec_wi = (const float*)d_in[5];
    const float* conv_w  = (const float*)d_in[6];
    const float* conv_b  = (const float*)d_in[7];
    const float* fc1_w   = (const float*)d_in[8];
    const float* fc1_b   = (const float*)d_in[9];
    const float* fc2_w   = (const float*)d_in[10];
    const float* fc2_b   = (const float*)d_in[11];
    float* preds = (float*)d_out;

    char* p = (char*)d_ws;
    float* seq = (float*)p;  p += (size_t)NB * SEQROWS * NR * 4;
    u16* ht1 = (u16*)p;  p += (size_t)2 * NB * NR * NW * 2;   // [2 buf][b][r][c] hi
    u16* ht2 = (u16*)p;  p += (size_t)2 * NB * NR * NW * 2;   // lo
    u16* htc1 = (u16*)p; p += (size_t)NB * NW * NR * 2;       // [b][c][r] hi
    u16* htc2 = (u16*)p; p += (size_t)NB * NW * NR * 2;       // lo
    u16* x1  = (u16*)p;  p += (size_t)128 * 4096 * 2;
    u16* x2  = (u16*)p;  p += (size_t)128 * 4096 * 2;
    u16* y1  = (u16*)p;  p += (size_t)NB * NW * 128 * 2;
    u16* y2  = (u16*)p;  p += (size_t)NB * NW * 128 * 2;
    u16* f1  = (u16*)p;  p += (size_t)128 * 512 * 2;
    u16* f2  = (u16*)p;  p += (size_t)128 * 512 * 2;
    u16* gt1 = (u16*)p;  p += (size_t)512 * 128 * 2;
    u16* gt2 = (u16*)p;  p += (size_t)512 * 128 * 2;
    u16* wr1 = (u16*)p;  p += (size_t)NLAY * NM * NW * NW * 2;
    u16* wr2 = (u16*)p;  p += (size_t)NLAY * NM * NW * NW * 2;
    u16* wi1 = (u16*)p;  p += (size_t)NLAY * NM * NW * NW * 2;
    u16* wi2 = (u16*)p;  p += (size_t)NLAY * NM * NW * NW * 2;
    u16* cw1 = (u16*)p;  p += (size_t)NLAY * NW * NW * 2;
    u16* cw2 = (u16*)p;  p += (size_t)NLAY * NW * NW * 2;
    u16* f11 = (u16*)p;  p += (size_t)256 * 128 * 2;
    u16* f12 = (u16*)p;  p += (size_t)256 * 128 * 2;

    const size_t htplane = (size_t)NB * NR * NW;

    setup_misc<<<2176, 256, 0, stream>>>(z, conv_w, fc1_w, f1, f2, gt1, gt2,
                                         cw1, cw2, f11, f12, seq);
    prep_specw<<<512, 256, 0, stream>>>(spec_wr, spec_wi, wr1, wr2, wi1, wi2);
    fc0_kernel<<<dim3(8, 32), 256, 0, stream>>>(seq, t_grid, fc0_w, fc0_b,
                                                ht1, ht2, htc1, htc2, 0);

    for (int step = 0; step < NSTEPS; step++) {
        int cur = 0;
        for (int l = 0; l < NLAY; l++) {
            const u16* hc1 = ht1 + (size_t)cur * htplane;
            const u16* hc2 = ht2 + (size_t)cur * htplane;
            u16* hn1 = ht1 + (size_t)(cur ^ 1) * htplane;
            u16* hn2 = ht2 + (size_t)(cur ^ 1) * htplane;
            dft_mfma<<<dim3(128, 4), 256, 0, stream>>>(f1, f2, htc1, htc2, x1, x2);
            modemix_mfma<<<dim3(64, 4), 256, 0, stream>>>(x1, x2, wr1, wr2, wi1, wi2,
                                                          y1, y2, l);
            if (l < 3) {
                idft_conv_mfma<<<dim3(8, 2, 32), 256, 0, stream>>>(y1, y2, gt1, gt2,
                                                                   hc1, hc2, cw1, cw2,
                                                                   conv_b, hn1, hn2,
                                                                   htc1, htc2, l);
            } else {
                // fused idft + head + fc0(next step); writes preds/seq and
                // next-step ht buffer0 + htc.
                idft_head_mfma<<<dim3(8, 32), 256, 0, stream>>>(
                    y1, y2, gt1, gt2, hc1, hc2, cw1, cw2, conv_b,
                    f11, f12, fc1_b, fc2_w, fc2_b, t_grid, fc0_w, fc0_b,
                    seq, preds, ht1, ht2, htc1, htc2,
                    l, step, (step < NSTEPS - 1) ? 1 : 0);
            }
            cur ^= 1;
        }
    }
}

// Round 16
// 1694.814 us; speedup vs baseline: 2.0966x; 1.0390x over previous
//
#include <hip/hip_runtime.h>
#include <math.h>

// LatentFNO: B=32, T=24, R=512, W=128, M=64 modes, 4 layers, 12 steps.
// Round 16: idft_head's head-GEMM had 8 serial global->LDS round trips
// (the r5 K-loop latency disease reintroduced). Fix: register-prefetch
// next fc1t chunk during current MFMA (same barrier count, latency off
// critical path); fc0-tail inputs (win/wl/bl) prefetched to registers
// during head phase. All other kernels byte-identical to r15.
// Math: exact 3-term bf16 split (A1B1+A1B2+A2B1).

#define NB 32
#define NR 512
#define NW 128
#define NM 64
#define NTH 24
#define NLAY 4
#define NSTEPS 12
#define SEQROWS 36

typedef unsigned short u16;
typedef unsigned int u32;
typedef __attribute__((ext_vector_type(8))) short bf16x8;
typedef __attribute__((ext_vector_type(4))) float f32x4;
#define MFMA16(a, b, c) __builtin_amdgcn_mfma_f32_16x16x32_bf16((a), (b), (c), 0, 0, 0)

__device__ __forceinline__ float gelu_exact(float x) {
    return 0.5f * x * (1.0f + erff(x * 0.70710678118654752f));
}
__device__ __forceinline__ float bf2f(u16 u) {
    union { u32 i; float f; } v; v.i = ((u32)u) << 16; return v.f;
}
__device__ __forceinline__ u16 f2bf_hi(float x) {
    union { float f; u32 i; } v; v.f = x; return (u16)(v.i >> 16);
}
__device__ __forceinline__ u16 f2bf_lo(float x) {
    float h = bf2f(f2bf_hi(x));
    return f2bf_hi(x - h);
}
__device__ __forceinline__ bf16x8 negbf(bf16x8 a) {
#pragma unroll
    for (int i = 0; i < 8; i++) a[i] ^= (short)0x8000;
    return a;
}

// ---------------------------------------------------------------------------
// Merged setup: DFT/iDFT tables + conv_w planes + fc1t planes + seq init.
// ---------------------------------------------------------------------------
__global__ void setup_misc(const float* __restrict__ z, const float* __restrict__ conv_w,
                           const float* __restrict__ fc1_w,
                           u16* __restrict__ f1, u16* __restrict__ f2,
                           u16* __restrict__ gt1, u16* __restrict__ gt2,
                           u16* __restrict__ cw1, u16* __restrict__ cw2,
                           u16* __restrict__ f11, u16* __restrict__ f12,
                           float* __restrict__ seq) {
    int idx = blockIdx.x * 256 + threadIdx.x;
    if (idx < 65536) {
        int mc = idx >> 9, r = idx & 511, m = mc & 63;
        int p = (m * r) & 511;
        float a = (float)p * (1.0f / 256.0f);
        float c = cospif(a), s = sinpif(a);
        float Fv = (mc < 64) ? c : -s;
        float cm = (m == 0) ? (1.0f / 512.0f) : (2.0f / 512.0f);
        float Gv = (mc < 64) ? cm * c : ((m == 0) ? 0.0f : -cm * s);
        f1[idx] = f2bf_hi(Fv); f2[idx] = f2bf_lo(Fv);
        size_t g = (size_t)r * 128 + mc;
        gt1[g] = f2bf_hi(Gv); gt2[g] = f2bf_lo(Gv);
    } else if (idx < 131072) {
        int i = idx - 65536;
        float v = conv_w[i];
        cw1[i] = f2bf_hi(v); cw2[i] = f2bf_lo(v);
    } else if (idx < 163840) {
        int i = idx - 131072;          // j*128 + c
        int j = i >> 7, c = i & 127;
        float v = fc1_w[(size_t)c * 256 + j];
        f11[i] = f2bf_hi(v); f12[i] = f2bf_lo(v);
    } else {
        int i = idx - 163840;          // < 32*24*512
        int b = i / (NTH * NR);
        int rem = i - b * (NTH * NR);
        seq[(size_t)b * SEQROWS * NR + rem] = z[i];
    }
}

// spec_w (l,i,o,m) -> planes [l][m][o][i] hi/lo, coalesced both directions.
__global__ __launch_bounds__(256) void prep_specw(const float* __restrict__ wr, const float* __restrict__ wi,
                           u16* __restrict__ wr1, u16* __restrict__ wr2,
                           u16* __restrict__ wi1, u16* __restrict__ wi2) {
    __shared__ float tile[128][65];
    int l = blockIdx.x >> 7, o = blockIdx.x & 127;
    int tid = threadIdx.x;
    size_t sbase = (size_t)l * 1048576 + (size_t)o * 64;
    size_t dbase = (size_t)l * 64 * 16384 + (size_t)o * 128;
    for (int pass = 0; pass < 2; pass++) {
        const float* src = pass ? wi : wr;
        u16* d1 = pass ? wi1 : wr1;
        u16* d2 = pass ? wi2 : wr2;
        if (pass) __syncthreads();
        for (int e = tid; e < 8192; e += 256) {
            int i = e >> 6, m = e & 63;
            tile[i][m] = src[sbase + (size_t)i * 8192 + m];
        }
        __syncthreads();
        for (int e = tid; e < 4096; e += 256) {
            int m = e >> 6, i2 = (e & 63) * 2;
            float v0 = tile[i2][m], v1 = tile[i2 + 1][m];
            u32 hh = (u32)f2bf_hi(v0) | ((u32)f2bf_hi(v1) << 16);
            u32 ll = (u32)f2bf_lo(v0) | ((u32)f2bf_lo(v1) << 16);
            size_t d = dbase + (size_t)m * 16384 + i2;
            *(u32*)&d1[d] = hh;
            *(u32*)&d2[d] = ll;
        }
    }
}

// ---------------------------------------------------------------------------
// fc0 (fp32), step 0 only: writes ht[b][r][c] AND htc[b][c][r] planes.
// ---------------------------------------------------------------------------
__global__ __launch_bounds__(256) void fc0_kernel(const float* __restrict__ seq,
        const float* __restrict__ t_grid, const float* __restrict__ fc0_w,
        const float* __restrict__ fc0_b, u16* __restrict__ ht1, u16* __restrict__ ht2,
        u16* __restrict__ htc1, u16* __restrict__ htc2, int step) {
    __shared__ float wlds[28 * 128];
    __shared__ float blds[128];
    int b = blockIdx.y, rblk = blockIdx.x;
    int tid = threadIdx.x;
    for (int t = tid; t < 28 * 128; t += 256) wlds[t] = fc0_w[t];
    if (tid < 128) blds[tid] = fc0_b[tid];
    __syncthreads();
    int lane = tid & 63, wq = tid >> 6;
    int r = rblk * 64 + lane;
    float sv[24];
    const float* sp = seq + ((size_t)b * SEQROWS + step) * NR + r;
#pragma unroll
    for (int t = 0; t < 24; t++) sv[t] = sp[(size_t)t * NR];
    float tt = t_grid[b * 24 + 23] + (float)(step + 1);
    float ang24 = 6.28318530717958647692f * tt * (1.0f / 24.0f);
    float ang168 = 6.28318530717958647692f * tt * (1.0f / 168.0f);
    float s24 = sinf(ang24), c24 = cosf(ang24), s168 = sinf(ang168);
    float xc = (float)r * (1.0f / 511.0f);
    size_t rowoff = ((size_t)b * NR + r) * NW;
#pragma unroll 2
    for (int w0 = 0; w0 < 32; w0 += 2) {
        float acc2[2];
#pragma unroll
        for (int q = 0; q < 2; q++) {
            int w = wq * 32 + w0 + q;
            float acc = blds[w];
#pragma unroll
            for (int t = 0; t < 24; t++) acc += sv[t] * wlds[t * 128 + w];
            acc += s24 * wlds[24 * 128 + w] + c24 * wlds[25 * 128 + w]
                 + s168 * wlds[26 * 128 + w] + xc * wlds[27 * 128 + w];
            acc2[q] = acc;
        }
        u16 h0 = f2bf_hi(acc2[0]), h1 = f2bf_hi(acc2[1]);
        u16 l0 = f2bf_lo(acc2[0]), l1 = f2bf_lo(acc2[1]);
        size_t off = rowoff + wq * 32 + w0;
        *(u32*)&ht1[off] = (u32)h0 | ((u32)h1 << 16);
        *(u32*)&ht2[off] = (u32)l0 | ((u32)l1 << 16);
        int w = wq * 32 + w0;
        size_t coff = ((size_t)b * 128 + w) * 512 + r;
        htc1[coff] = h0; htc1[coff + 512] = h1;
        htc2[coff] = l0; htc2[coff + 512] = l1;
    }
}

// ---------------------------------------------------------------------------
// dft (MFMA): X[128][4096] = F * htc^T, K=512, BK=64, depth-3 pipelined.
// grid (128 n-tiles of 32, 4 mc-tiles) = 512 blocks (2/CU).
// ---------------------------------------------------------------------------
__global__ __launch_bounds__(256) void dft_mfma(const u16* __restrict__ f1, const u16* __restrict__ f2,
        const u16* __restrict__ htc1, const u16* __restrict__ htc2,
        u16* __restrict__ x1, u16* __restrict__ x2) {
    __shared__ __align__(16) u16 A1[2][32 * 72], A2[2][32 * 72];
    __shared__ __align__(16) u16 B1[2][32 * 72], B2[2][32 * 72];
    int bx = blockIdx.x;
    int mct = blockIdx.y * 32;
    int tid = threadIdx.x, wid = tid >> 6, l = tid & 63;
    int wm0 = (wid >> 1) * 16, wn0 = (wid & 1) * 16;
    int arow = l & 15, kgrp = (l >> 4) * 8;
    f32x4 acc = {0.f, 0.f, 0.f, 0.f};
    int pl = tid >> 7, row = (tid >> 2) & 31, sp = (tid & 3) * 16;
    const u16* asrc = (pl ? f2 : f1) + (size_t)(mct + row) * 512 + sp;
    const u16* bsrc = (pl ? htc2 : htc1)
                      + ((size_t)(bx >> 2) * 128 + (bx & 3) * 32 + row) * 512 + sp;
    int loff = row * 72 + sp;
    u16* ad0 = (pl ? A2[0] : A1[0]) + loff;  u16* ad1 = (pl ? A2[1] : A1[1]) + loff;
    u16* bd0 = (pl ? B2[0] : B1[0]) + loff;  u16* bd1 = (pl ? B2[1] : B1[1]) + loff;
    uint4 oA0, oA1, oB0, oB1, eA0, eA1, eB0, eB1;
    oA0 = *(const uint4*)(asrc);     oA1 = *(const uint4*)(asrc + 8);
    oB0 = *(const uint4*)(bsrc);     oB1 = *(const uint4*)(bsrc + 8);
    *(uint4*)ad0 = oA0; *(uint4*)(ad0 + 8) = oA1;
    *(uint4*)bd0 = oB0; *(uint4*)(bd0 + 8) = oB1;
    oA0 = *(const uint4*)(asrc + 64);  oA1 = *(const uint4*)(asrc + 72);
    oB0 = *(const uint4*)(bsrc + 64);  oB1 = *(const uint4*)(bsrc + 72);
    eA0 = *(const uint4*)(asrc + 128); eA1 = *(const uint4*)(asrc + 136);
    eB0 = *(const uint4*)(bsrc + 128); eB1 = *(const uint4*)(bsrc + 136);
    __syncthreads();
#define DFT_COMPUTE(BUF)                                                       \
    { _Pragma("unroll")                                                        \
      for (int kk = 0; kk < 64; kk += 32) {                                    \
        bf16x8 a1 = *(const bf16x8*)&A1[BUF][(wm0 + arow) * 72 + kk + kgrp];   \
        bf16x8 a2 = *(const bf16x8*)&A2[BUF][(wm0 + arow) * 72 + kk + kgrp];   \
        bf16x8 b1 = *(const bf16x8*)&B1[BUF][(wn0 + arow) * 72 + kk + kgrp];   \
        bf16x8 b2 = *(const bf16x8*)&B2[BUF][(wn0 + arow) * 72 + kk + kgrp];   \
        acc = MFMA16(a1, b1, acc);                                             \
        acc = MFMA16(a1, b2, acc);                                             \
        acc = MFMA16(a2, b1, acc);                                             \
      } }
    for (int k = 0; k < 8; k += 2) {
        DFT_COMPUTE(0)
        *(uint4*)ad1 = oA0; *(uint4*)(ad1 + 8) = oA1;
        *(uint4*)bd1 = oB0; *(uint4*)(bd1 + 8) = oB1;
        if (k < 5) {
            int ko = (k + 3) * 64;
            oA0 = *(const uint4*)(asrc + ko);      oA1 = *(const uint4*)(asrc + ko + 8);
            oB0 = *(const uint4*)(bsrc + ko);      oB1 = *(const uint4*)(bsrc + ko + 8);
        }
        __syncthreads();
        DFT_COMPUTE(1)
        if (k < 6) {
            *(uint4*)ad0 = eA0; *(uint4*)(ad0 + 8) = eA1;
            *(uint4*)bd0 = eB0; *(uint4*)(bd0 + 8) = eB1;
            if (k < 4) {
                int ko = (k + 4) * 64;
                eA0 = *(const uint4*)(asrc + ko);  eA1 = *(const uint4*)(asrc + ko + 8);
                eB0 = *(const uint4*)(bsrc + ko);  eB1 = *(const uint4*)(bsrc + ko + 8);
            }
        }
        __syncthreads();
    }
#undef DFT_COMPUTE
    int mcr = mct + wm0 + (l >> 4) * 4;
    int n0 = bx * 32 + wn0 + (l & 15);
#pragma unroll
    for (int j = 0; j < 4; j++) {
        size_t o0 = (size_t)(mcr + j) * 4096 + n0;
        x1[o0] = f2bf_hi(acc[j]); x2[o0] = f2bf_lo(acc[j]);
    }
}

// ---------------------------------------------------------------------------
// modemix (MFMA, single-barrier): Y = W *c X per mode, K=128 fully in LDS.
// grid (64 m, 4 oq), 256 thr.
// ---------------------------------------------------------------------------
__global__ __launch_bounds__(256) void modemix_mfma(const u16* __restrict__ x1, const u16* __restrict__ x2,
        const u16* __restrict__ wr1, const u16* __restrict__ wr2,
        const u16* __restrict__ wi1, const u16* __restrict__ wi2,
        u16* __restrict__ y1, u16* __restrict__ y2, int layer) {
    __shared__ __align__(16) u16 POOL[8 * 32 * 136];
    int m = blockIdx.x, oq = blockIdx.y;
    int tid = threadIdx.x, wid = tid >> 6, l = tid & 63;
    int wo0 = (wid >> 1) * 16, wb0 = (wid & 1) * 16;
    int arow = l & 15, kgrp = (l >> 4) * 8;
    size_t wbase = (((size_t)layer * 64 + m) * 128 + oq * 32) * 128;
#pragma unroll
    for (int q = 0; q < 16; q++) {
        const int slab = q >> 1;
        int rr = ((q & 1) << 4) + (tid >> 4);
        int seg = tid & 15;
        const u16* src;
        if      (slab == 0) src = wr1 + wbase + (size_t)rr * 128 + seg * 8;
        else if (slab == 1) src = wr2 + wbase + (size_t)rr * 128 + seg * 8;
        else if (slab == 2) src = wi1 + wbase + (size_t)rr * 128 + seg * 8;
        else if (slab == 3) src = wi2 + wbase + (size_t)rr * 128 + seg * 8;
        else if (slab == 4) src = x1 + (size_t)m * 4096 + rr * 128 + seg * 8;
        else if (slab == 5) src = x2 + (size_t)m * 4096 + rr * 128 + seg * 8;
        else if (slab == 6) src = x1 + (size_t)(64 + m) * 4096 + rr * 128 + seg * 8;
        else                src = x2 + (size_t)(64 + m) * 4096 + rr * 128 + seg * 8;
        *(uint4*)&POOL[slab * 4352 + rr * 136 + seg * 8] = *(const uint4*)src;
    }
    __syncthreads();
    f32x4 ar = {0.f, 0.f, 0.f, 0.f}, ai = {0.f, 0.f, 0.f, 0.f};
    int aoB = (wo0 + arow) * 136 + kgrp;
    int boB = (wb0 + arow) * 136 + kgrp;
#pragma unroll
    for (int kg = 0; kg < 4; kg++) {
        int ao = aoB + kg * 32;
        int bo = boB + kg * 32;
        bf16x8 Wr1 = *(const bf16x8*)&POOL[0 * 4352 + ao];
        bf16x8 Wr2 = *(const bf16x8*)&POOL[1 * 4352 + ao];
        bf16x8 Wi1 = *(const bf16x8*)&POOL[2 * 4352 + ao];
        bf16x8 Wi2 = *(const bf16x8*)&POOL[3 * 4352 + ao];
        bf16x8 Xr1 = *(const bf16x8*)&POOL[4 * 4352 + bo];
        bf16x8 Xr2 = *(const bf16x8*)&POOL[5 * 4352 + bo];
        bf16x8 Xi1 = *(const bf16x8*)&POOL[6 * 4352 + bo];
        bf16x8 Xi2 = *(const bf16x8*)&POOL[7 * 4352 + bo];
        bf16x8 nWi1 = negbf(Wi1), nWi2 = negbf(Wi2);
        ar = MFMA16(Wr1, Xr1, ar); ar = MFMA16(Wr1, Xr2, ar); ar = MFMA16(Wr2, Xr1, ar);
        ar = MFMA16(nWi1, Xi1, ar); ar = MFMA16(nWi1, Xi2, ar); ar = MFMA16(nWi2, Xi1, ar);
        ai = MFMA16(Wi1, Xr1, ai); ai = MFMA16(Wi1, Xr2, ai); ai = MFMA16(Wi2, Xr1, ai);
        ai = MFMA16(Wr1, Xi1, ai); ai = MFMA16(Wr1, Xi2, ai); ai = MFMA16(Wr2, Xi1, ai);
    }
    int ob = oq * 32 + wo0 + (l >> 4) * 4;
    int bb = wb0 + (l & 15);
#pragma unroll
    for (int j = 0; j < 4; j++) {
        size_t o = ((size_t)bb * 128 + ob + j) * 128;
        y1[o + m] = f2bf_hi(ar[j]); y2[o + m] = f2bf_lo(ar[j]);
        y1[o + 64 + m] = f2bf_hi(ai[j]); y2[o + 64 + m] = f2bf_lo(ai[j]);
    }
}

// ---------------------------------------------------------------------------
// idft+conv (layers 0..2): C[o][r] = [Y|CW](o,256)*[GT;ht](256,r)+bias,GELU.
// grid (8 rt, 2 ot, 32 b). T-transpose epilogue writes htc.
// ---------------------------------------------------------------------------
__global__ __launch_bounds__(256) void idft_conv_mfma(const u16* __restrict__ y1, const u16* __restrict__ y2,
        const u16* __restrict__ gt1, const u16* __restrict__ gt2,
        const u16* __restrict__ hc1, const u16* __restrict__ hc2,
        const u16* __restrict__ cw1, const u16* __restrict__ cw2,
        const float* __restrict__ conv_b,
        u16* __restrict__ hn1, u16* __restrict__ hn2,
        u16* __restrict__ htc1, u16* __restrict__ htc2, int layer) {
    __shared__ __align__(16) u16 A1[2][2560], A2[2][2560];
    __shared__ __align__(16) u16 B1[2][2560], B2[2][2560];
    __shared__ __align__(16) u16 T1[64 * 66], T2[64 * 66];
    int rt = blockIdx.x * 64, ot = blockIdx.y * 64, b = blockIdx.z;
    int tid = threadIdx.x, wid = tid >> 6, l = tid & 63;
    int wo0 = (wid >> 1) * 32, wr0 = (wid & 1) * 32;
    int arow = (l & 15), kgrp = (l >> 4) * 8;
    int srow = (tid >> 2) & 63, sseg = tid & 3;
    int soff = srow * 40 + sseg * 8;
    const u16* ya = y1 + ((size_t)b * 128 + ot + srow) * 128 + sseg * 8;
    const u16* yb = y2 + ((size_t)b * 128 + ot + srow) * 128 + sseg * 8;
    const u16* ca = cw1 + ((size_t)layer * 128 + ot + srow) * 128 + sseg * 8;
    const u16* cb = cw2 + ((size_t)layer * 128 + ot + srow) * 128 + sseg * 8;
    const u16* ga = gt1 + (size_t)(rt + srow) * 128 + sseg * 8;
    const u16* gb = gt2 + (size_t)(rt + srow) * 128 + sseg * 8;
    const u16* ha = hc1 + ((size_t)b * 512 + rt + srow) * 128 + sseg * 8;
    const u16* hb = hc2 + ((size_t)b * 512 + rt + srow) * 128 + sseg * 8;
    f32x4 acc[2][2] = {{{0.f,0.f,0.f,0.f},{0.f,0.f,0.f,0.f}},{{0.f,0.f,0.f,0.f},{0.f,0.f,0.f,0.f}}};
    uint4 raO0, raO1, rbO0, rbO1, raE0, raE1, rbE0, rbE1;
#define ILOAD(chk, Ra0, Ra1, Rb0, Rb1)                                        \
    {   int k0_ = ((chk) & 3) * 32;                                           \
        if ((chk) < 4) {                                                      \
            Ra0 = *(const uint4*)(ya + k0_); Ra1 = *(const uint4*)(yb + k0_); \
            Rb0 = *(const uint4*)(ga + k0_); Rb1 = *(const uint4*)(gb + k0_); \
        } else {                                                              \
            Ra0 = *(const uint4*)(ca + k0_); Ra1 = *(const uint4*)(cb + k0_); \
            Rb0 = *(const uint4*)(ha + k0_); Rb1 = *(const uint4*)(hb + k0_); \
        } }
#define ISTORE(BUF, Ra0, Ra1, Rb0, Rb1)                                      \
    {   *(uint4*)(A1[BUF] + soff) = Ra0; *(uint4*)(A2[BUF] + soff) = Ra1;     \
        *(uint4*)(B1[BUF] + soff) = Rb0; *(uint4*)(B2[BUF] + soff) = Rb1; }
#define ICOMP(BUF)                                                            \
    {   bf16x8 bfr[2][2];                                                     \
        _Pragma("unroll")                                                     \
        for (int rf = 0; rf < 2; rf++) {                                      \
            bfr[rf][0] = *(const bf16x8*)&B1[BUF][(wr0 + rf * 16 + arow) * 40 + kgrp]; \
            bfr[rf][1] = *(const bf16x8*)&B2[BUF][(wr0 + rf * 16 + arow) * 40 + kgrp]; \
        }                                                                     \
        _Pragma("unroll")                                                     \
        for (int of = 0; of < 2; of++) {                                      \
            bf16x8 a1 = *(const bf16x8*)&A1[BUF][(wo0 + of * 16 + arow) * 40 + kgrp]; \
            bf16x8 a2 = *(const bf16x8*)&A2[BUF][(wo0 + of * 16 + arow) * 40 + kgrp]; \
            _Pragma("unroll")                                                 \
            for (int rf = 0; rf < 2; rf++) {                                  \
                acc[of][rf] = MFMA16(a1, bfr[rf][0], acc[of][rf]);            \
                acc[of][rf] = MFMA16(a1, bfr[rf][1], acc[of][rf]);            \
                acc[of][rf] = MFMA16(a2, bfr[rf][0], acc[of][rf]);            \
            }                                                                 \
        } }
    ILOAD(0, raO0, raO1, rbO0, rbO1)
    ISTORE(0, raO0, raO1, rbO0, rbO1)
    ILOAD(1, raO0, raO1, rbO0, rbO1)
    ILOAD(2, raE0, raE1, rbE0, rbE1)
    __syncthreads();
    for (int k = 0; k < 8; k += 2) {
        ICOMP(0)
        ISTORE(1, raO0, raO1, rbO0, rbO1)
        if (k < 5) ILOAD(k + 3, raO0, raO1, rbO0, rbO1)
        __syncthreads();
        ICOMP(1)
        if (k < 6) {
            ISTORE(0, raE0, raE1, rbE0, rbE1)
            if (k < 4) ILOAD(k + 4, raE0, raE1, rbE0, rbE1)
        }
        __syncthreads();
    }
#undef ILOAD
#undef ISTORE
#undef ICOMP
#pragma unroll
    for (int of = 0; of < 2; of++) {
        int obl = wo0 + of * 16 + (l >> 4) * 4;
        int ob = ot + obl;
#pragma unroll
        for (int rf = 0; rf < 2; rf++) {
            int rloc = wr0 + rf * 16 + (l & 15);
            int r = rt + rloc;
            float v0 = gelu_exact(acc[of][rf][0] + conv_b[layer * 128 + ob + 0]);
            float v1 = gelu_exact(acc[of][rf][1] + conv_b[layer * 128 + ob + 1]);
            float v2 = gelu_exact(acc[of][rf][2] + conv_b[layer * 128 + ob + 2]);
            float v3 = gelu_exact(acc[of][rf][3] + conv_b[layer * 128 + ob + 3]);
            ushort4 hv, lv;
            hv.x = f2bf_hi(v0); hv.y = f2bf_hi(v1); hv.z = f2bf_hi(v2); hv.w = f2bf_hi(v3);
            lv.x = f2bf_lo(v0); lv.y = f2bf_lo(v1); lv.z = f2bf_lo(v2); lv.w = f2bf_lo(v3);
            size_t off = ((size_t)b * 512 + r) * 128 + ob;
            *(ushort4*)&hn1[off] = hv;
            *(ushort4*)&hn2[off] = lv;
            T1[(obl + 0) * 66 + rloc] = hv.x; T1[(obl + 1) * 66 + rloc] = hv.y;
            T1[(obl + 2) * 66 + rloc] = hv.z; T1[(obl + 3) * 66 + rloc] = hv.w;
            T2[(obl + 0) * 66 + rloc] = lv.x; T2[(obl + 1) * 66 + rloc] = lv.y;
            T2[(obl + 2) * 66 + rloc] = lv.z; T2[(obl + 3) * 66 + rloc] = lv.w;
        }
    }
    __syncthreads();
#pragma unroll
    for (int q = 0; q < 8; q++) {
        int t = tid + q * 256;
        int o = t >> 5, ru = t & 31;
        u32 vh = *(const u32*)&T1[o * 66 + ru * 2];
        u32 vl = *(const u32*)&T2[o * 66 + ru * 2];
        size_t off = ((size_t)b * 128 + ot + o) * 512 + rt + ru * 2;
        *(u32*)&htc1[off] = vh;
        *(u32*)&htc2[off] = vl;
    }
}

// ---------------------------------------------------------------------------
// Layer-3 fused: idft+conv (all 128 o) -> h in LDS -> head (pipelined fc1t
// staging) -> z update -> fc0 next step (inputs reg-prefetched).
// grid (8 rt, 32 b) = 256 blocks. Bit-identical j/k accumulation order.
// ---------------------------------------------------------------------------
__global__ __launch_bounds__(256) void idft_head_mfma(
        const u16* __restrict__ y1, const u16* __restrict__ y2,
        const u16* __restrict__ gt1, const u16* __restrict__ gt2,
        const u16* __restrict__ hc1, const u16* __restrict__ hc2,
        const u16* __restrict__ cw1, const u16* __restrict__ cw2,
        const float* __restrict__ conv_b,
        const u16* __restrict__ f11, const u16* __restrict__ f12,
        const float* __restrict__ fc1_b, const float* __restrict__ fc2_w,
        const float* __restrict__ fc2_b,
        const float* __restrict__ t_grid, const float* __restrict__ fc0_w,
        const float* __restrict__ fc0_b,
        float* __restrict__ seq, float* __restrict__ preds,
        u16* __restrict__ nht1, u16* __restrict__ nht2,
        u16* __restrict__ nhtc1, u16* __restrict__ nhtc2,
        int layer, int step, int do_fc0) {
    __shared__ __align__(16) u16 POOL[35072];   // 70144 B
    int rt = blockIdx.x * 64, b = blockIdx.y;
    int tid = threadIdx.x, wid = tid >> 6, l = tid & 63;
    int wo0 = (wid >> 1) * 32, wr0 = (wid & 1) * 32;
    int arow = (l & 15), kgrp = (l >> 4) * 8;
    u16* A1 = POOL;                  // [2][5120]
    u16* A2 = POOL + 10240;
    u16* B1 = POOL + 20480;          // [2][2560]
    u16* B2 = POOL + 25600;
    int srow = tid >> 2, sseg = tid & 3;
    const u16* ya0 = y1 + ((size_t)b * 128 + srow) * 128 + sseg * 8;
    const u16* ya1 = ya0 + 64 * 128;
    const u16* yb0 = y2 + ((size_t)b * 128 + srow) * 128 + sseg * 8;
    const u16* yb1 = yb0 + 64 * 128;
    const u16* ca0 = cw1 + ((size_t)layer * 128 + srow) * 128 + sseg * 8;
    const u16* ca1 = ca0 + 64 * 128;
    const u16* cb0 = cw2 + ((size_t)layer * 128 + srow) * 128 + sseg * 8;
    const u16* cb1 = cb0 + 64 * 128;
    const u16* ga = gt1 + (size_t)(rt + srow) * 128 + sseg * 8;
    const u16* gb = gt2 + (size_t)(rt + srow) * 128 + sseg * 8;
    const u16* ha = hc1 + ((size_t)b * 512 + rt + srow) * 128 + sseg * 8;
    const u16* hb = hc2 + ((size_t)b * 512 + rt + srow) * 128 + sseg * 8;
    int soffA0 = srow * 40 + sseg * 8;
    int soffA1 = (srow + 64) * 40 + sseg * 8;
    f32x4 acc[2][2][2];
#pragma unroll
    for (int ot = 0; ot < 2; ot++)
#pragma unroll
        for (int of = 0; of < 2; of++)
#pragma unroll
            for (int rf = 0; rf < 2; rf++) acc[ot][of][rf] = (f32x4){0.f, 0.f, 0.f, 0.f};
    uint4 oA0, oA1r, oA2r, oA3, oB0, oB1;
    uint4 eA0, eA1r, eA2r, eA3, eB0, eB1;
#define ILOAD(chk, Q0, Q1, Q2, Q3, R0, R1)                                    \
    {   int k0_ = ((chk) & 3) * 32;                                           \
        if ((chk) < 4) {                                                      \
            Q0 = *(const uint4*)(ya0 + k0_); Q1 = *(const uint4*)(ya1 + k0_); \
            Q2 = *(const uint4*)(yb0 + k0_); Q3 = *(const uint4*)(yb1 + k0_); \
            R0 = *(const uint4*)(ga + k0_);  R1 = *(const uint4*)(gb + k0_);  \
        } else {                                                              \
            Q0 = *(const uint4*)(ca0 + k0_); Q1 = *(const uint4*)(ca1 + k0_); \
            Q2 = *(const uint4*)(cb0 + k0_); Q3 = *(const uint4*)(cb1 + k0_); \
            R0 = *(const uint4*)(ha + k0_);  R1 = *(const uint4*)(hb + k0_);  \
        } }
#define ISTORE(BUF, Q0, Q1, Q2, Q3, R0, R1)                                   \
    {   *(uint4*)(A1 + (BUF) * 5120 + soffA0) = Q0;                           \
        *(uint4*)(A1 + (BUF) * 5120 + soffA1) = Q1;                           \
        *(uint4*)(A2 + (BUF) * 5120 + soffA0) = Q2;                           \
        *(uint4*)(A2 + (BUF) * 5120 + soffA1) = Q3;                           \
        *(uint4*)(B1 + (BUF) * 2560 + soffA0) = R0;                           \
        *(uint4*)(B2 + (BUF) * 2560 + soffA0) = R1; }
#define ICOMP(BUF)                                                            \
    {   bf16x8 bfr[2][2];                                                     \
        _Pragma("unroll")                                                     \
        for (int rf = 0; rf < 2; rf++) {                                      \
            bfr[rf][0] = *(const bf16x8*)&B1[(BUF) * 2560 + (wr0 + rf * 16 + arow) * 40 + kgrp]; \
            bfr[rf][1] = *(const bf16x8*)&B2[(BUF) * 2560 + (wr0 + rf * 16 + arow) * 40 + kgrp]; \
        }                                                                     \
        _Pragma("unroll")                                                     \
        for (int ot = 0; ot < 2; ot++) {                                      \
        _Pragma("unroll")                                                     \
        for (int of = 0; of < 2; of++) {                                      \
            bf16x8 a1v = *(const bf16x8*)&A1[(BUF) * 5120 + (ot * 64 + wo0 + of * 16 + arow) * 40 + kgrp]; \
            bf16x8 a2v = *(const bf16x8*)&A2[(BUF) * 5120 + (ot * 64 + wo0 + of * 16 + arow) * 40 + kgrp]; \
            _Pragma("unroll")                                                 \
            for (int rf = 0; rf < 2; rf++) {                                  \
                acc[ot][of][rf] = MFMA16(a1v, bfr[rf][0], acc[ot][of][rf]);   \
                acc[ot][of][rf] = MFMA16(a1v, bfr[rf][1], acc[ot][of][rf]);   \
                acc[ot][of][rf] = MFMA16(a2v, bfr[rf][0], acc[ot][of][rf]);   \
            }                                                                 \
        } } }
    ILOAD(0, oA0, oA1r, oA2r, oA3, oB0, oB1)
    ISTORE(0, oA0, oA1r, oA2r, oA3, oB0, oB1)
    ILOAD(1, oA0, oA1r, oA2r, oA3, oB0, oB1)
    ILOAD(2, eA0, eA1r, eA2r, eA3, eB0, eB1)
    __syncthreads();
    for (int k = 0; k < 8; k += 2) {
        ICOMP(0)
        ISTORE(1, oA0, oA1r, oA2r, oA3, oB0, oB1)
        if (k < 5) ILOAD(k + 3, oA0, oA1r, oA2r, oA3, oB0, oB1)
        __syncthreads();
        ICOMP(1)
        if (k < 6) {
            ISTORE(0, eA0, eA1r, eA2r, eA3, eB0, eB1)
            if (k < 4) ILOAD(k + 4, eA0, eA1r, eA2r, eA3, eB0, eB1)
        }
        __syncthreads();
    }
#undef ILOAD
#undef ISTORE
#undef ICOMP
    __syncthreads();                 // A/B reads done; alias h over POOL
    u16* h1 = POOL;                  // [64][136] hi
    u16* h2 = POOL + 8704;           // [64][136] lo
#pragma unroll
    for (int ot = 0; ot < 2; ot++) {
#pragma unroll
        for (int of = 0; of < 2; of++) {
            int obl = ot * 64 + wo0 + of * 16 + (l >> 4) * 4;
#pragma unroll
            for (int rf = 0; rf < 2; rf++) {
                int rloc = wr0 + rf * 16 + (l & 15);
                float v0 = gelu_exact(acc[ot][of][rf][0] + conv_b[layer * 128 + obl + 0]);
                float v1 = gelu_exact(acc[ot][of][rf][1] + conv_b[layer * 128 + obl + 1]);
                float v2 = gelu_exact(acc[ot][of][rf][2] + conv_b[layer * 128 + obl + 2]);
                float v3 = gelu_exact(acc[ot][of][rf][3] + conv_b[layer * 128 + obl + 3]);
                ushort4 hv, lv;
                hv.x = f2bf_hi(v0); hv.y = f2bf_hi(v1); hv.z = f2bf_hi(v2); hv.w = f2bf_hi(v3);
                lv.x = f2bf_lo(v0); lv.y = f2bf_lo(v1); lv.z = f2bf_lo(v2); lv.w = f2bf_lo(v3);
                *(ushort4*)&h1[rloc * 136 + obl] = hv;
                *(ushort4*)&h2[rloc * 136 + obl] = lv;
            }
        }
    }
    // ---- head: D[j][r] = fc1t(j,c)*h(r,c); dx = sum_j gelu(D+b1)*w2 ----
    // fc1t staging pipelined: register-prefetch next chunk during MFMA.
    u16* HA1 = POOL + 17408;         // [128][40]
    u16* HA2 = POOL + 22528;
    float* fc2s = (float*)(POOL + 27648);    // 256 f (bytes 55296..)
    float* fc1bs = (float*)(POOL + 28160);   // 256 f
    fc2s[tid] = fc2_w[tid];
    fc1bs[tid] = fc1_b[tid];
    int j0 = tid >> 2, segh = tid & 3;
    const u16* fa = f11 + (size_t)j0 * 128 + segh * 8;
    const u16* fb = f12 + (size_t)j0 * 128 + segh * 8;
    int haoff = j0 * 40 + segh * 8;
    uint4 pr0, pr1, pr2, pr3;
#define HLOAD(JH, K0)                                                         \
    {   size_t o_ = (size_t)(JH) * 128 * 128 + (K0);                          \
        pr0 = *(const uint4*)(fa + o_);                                       \
        pr1 = *(const uint4*)(fa + o_ + 64 * 128);                            \
        pr2 = *(const uint4*)(fb + o_);                                       \
        pr3 = *(const uint4*)(fb + o_ + 64 * 128); }
#define HSTORE()                                                              \
    {   *(uint4*)(HA1 + haoff) = pr0;                                         \
        *(uint4*)(HA1 + haoff + 64 * 40) = pr1;                               \
        *(uint4*)(HA2 + haoff) = pr2;                                         \
        *(uint4*)(HA2 + haoff + 64 * 40) = pr3; }
    float dx = 0.0f;
    HLOAD(0, 0)
    for (int jh = 0; jh < 2; jh++) {
        f32x4 hacc[8];
#pragma unroll
        for (int jf = 0; jf < 8; jf++) hacc[jf] = (f32x4){0.f, 0.f, 0.f, 0.f};
        for (int k0 = 0; k0 < 128; k0 += 32) {
            __syncthreads();          // prior chunk's MFMA done reading HA
            HSTORE()
            __syncthreads();          // HA ready
            if (k0 < 96) { HLOAD(jh, k0 + 32) }
            else if (jh == 0) { HLOAD(1, 0) }
            int bo = (wid * 16 + arow) * 136 + k0 + kgrp;
            bf16x8 hb1 = *(const bf16x8*)&h1[bo];
            bf16x8 hb2 = *(const bf16x8*)&h2[bo];
#pragma unroll
            for (int jf = 0; jf < 8; jf++) {
                int ao = (jf * 16 + arow) * 40 + kgrp;
                bf16x8 a1 = *(const bf16x8*)&HA1[ao];
                bf16x8 a2 = *(const bf16x8*)&HA2[ao];
                hacc[jf] = MFMA16(a1, hb1, hacc[jf]);
                hacc[jf] = MFMA16(a1, hb2, hacc[jf]);
                hacc[jf] = MFMA16(a2, hb1, hacc[jf]);
            }
        }
#pragma unroll
        for (int jf = 0; jf < 8; jf++) {
            int jbase = jh * 128 + jf * 16 + (l >> 4) * 4;
#pragma unroll
            for (int jj = 0; jj < 4; jj++) {
                dx += gelu_exact(hacc[jf][jj] + fc1bs[jbase + jj]) * fc2s[jbase + jj];
            }
        }
    }
#undef HLOAD
#undef HSTORE
    // prefetch fc0-tail inputs into registers (independent of zn)
    float winreg[6], wlreg[14], blreg = 0.0f;
    if (do_fc0) {
#pragma unroll
        for (int q = 0; q < 6; q++) {
            int t2 = tid + q * 256;
            winreg[q] = 0.0f;
            if (t2 < 1472) {
                int tr = t2 >> 6, c = t2 & 63;
                winreg[q] = seq[((size_t)b * SEQROWS + step + 1 + tr) * NR + rt + c];
            }
        }
#pragma unroll
        for (int q = 0; q < 14; q++) wlreg[q] = fc0_w[tid + q * 256];
        if (tid < 128) blreg = fc0_b[tid];
    }
    dx += __shfl_xor(dx, 16);
    dx += __shfl_xor(dx, 32);
    bool zlane = ((l >> 4) == 0);
    int rml = wid * 16 + arow;
    float zn = 0.0f;
    if (zlane) {
        int r = rt + rml;
        zn = seq[((size_t)b * SEQROWS + step + 23) * NR + r] + dx + fc2_b[0];
        seq[((size_t)b * SEQROWS + step + 24) * NR + r] = zn;
        preds[((size_t)b * NSTEPS + step) * NR + r] = zn;
    }
    if (do_fc0) {
        float* win = (float*)POOL;                 // [24][64]
        float* wl  = (float*)POOL + 2048;          // [28][128]
        float* bl  = (float*)POOL + 2048 + 3584;   // [128]
        __syncthreads();   // all h/HA LDS reads done before aliasing
#pragma unroll
        for (int q = 0; q < 6; q++) {
            int t2 = tid + q * 256;
            if (t2 < 1472) win[t2] = winreg[q];
        }
#pragma unroll
        for (int q = 0; q < 14; q++) wl[tid + q * 256] = wlreg[q];
        if (tid < 128) bl[tid] = blreg;
        if (zlane) win[23 * 64 + rml] = zn;
        __syncthreads();
        int lane = tid & 63, wq = tid >> 6;
        int r = rt + lane;
        float sv[24];
#pragma unroll
        for (int t = 0; t < 24; t++) sv[t] = win[t * 64 + lane];
        float tt = t_grid[b * 24 + 23] + (float)(step + 2);
        float ang24 = 6.28318530717958647692f * tt * (1.0f / 24.0f);
        float ang168 = 6.28318530717958647692f * tt * (1.0f / 168.0f);
        float s24 = sinf(ang24), c24 = cosf(ang24), s168 = sinf(ang168);
        float xc = (float)r * (1.0f / 511.0f);
        size_t rowoff = ((size_t)b * NR + r) * NW;
#pragma unroll 2
        for (int w0 = 0; w0 < 32; w0 += 2) {
            float acc2[2];
#pragma unroll
            for (int q = 0; q < 2; q++) {
                int w = wq * 32 + w0 + q;
                float a = bl[w];
#pragma unroll
                for (int t = 0; t < 24; t++) a += sv[t] * wl[t * 128 + w];
                a += s24 * wl[24 * 128 + w] + c24 * wl[25 * 128 + w]
                   + s168 * wl[26 * 128 + w] + xc * wl[27 * 128 + w];
                acc2[q] = a;
            }
            u16 h0 = f2bf_hi(acc2[0]), h1v = f2bf_hi(acc2[1]);
            u16 l0 = f2bf_lo(acc2[0]), l1v = f2bf_lo(acc2[1]);
            size_t off = rowoff + wq * 32 + w0;
            *(u32*)&nht1[off] = (u32)h0 | ((u32)h1v << 16);
            *(u32*)&nht2[off] = (u32)l0 | ((u32)l1v << 16);
            int w = wq * 32 + w0;
            size_t coff = ((size_t)b * 128 + w) * 512 + r;
            nhtc1[coff] = h0; nhtc1[coff + 512] = h1v;
            nhtc2[coff] = l0; nhtc2[coff + 512] = l1v;
        }
    }
}

// ---------------------------------------------------------------------------
extern "C" void kernel_launch(void* const* d_in, const int* in_sizes, int n_in,
                              void* d_out, int out_size, void* d_ws, size_t ws_size,
                              hipStream_t stream) {
    (void)in_sizes; (void)n_in; (void)out_size; (void)ws_size;
    const float* z       = (const float*)d_in[0];
    const float* t_grid  = (const float*)d_in[1];
    const float* fc0_w   = (const float*)d_in[2];
    const float* fc0_b   = (const float*)d_in[3];
    const float* spec_wr = (const float*)d_in[4];
    const float* spec_wi = (const float*)d_in[5];
    const float* conv_w  = (const float*)d_in[6];
    const float* conv_b  = (const float*)d_in[7];
    const float* fc1_w   = (const float*)d_in[8];
    const float* fc1_b   = (const float*)d_in[9];
    const float* fc2_w   = (const float*)d_in[10];
    const float* fc2_b   = (const float*)d_in[11];
    float* preds = (float*)d_out;

    char* p = (char*)d_ws;
    float* seq = (float*)p;  p += (size_t)NB * SEQROWS * NR * 4;
    u16* ht1 = (u16*)p;  p += (size_t)2 * NB * NR * NW * 2;   // [2 buf][b][r][c] hi
    u16* ht2 = (u16*)p;  p += (size_t)2 * NB * NR * NW * 2;   // lo
    u16* htc1 = (u16*)p; p += (size_t)NB * NW * NR * 2;       // [b][c][r] hi
    u16* htc2 = (u16*)p; p += (size_t)NB * NW * NR * 2;       // lo
    u16* x1  = (u16*)p;  p += (size_t)128 * 4096 * 2;
    u16* x2  = (u16*)p;  p += (size_t)128 * 4096 * 2;
    u16* y1  = (u16*)p;  p += (size_t)NB * NW * 128 * 2;
    u16* y2  = (u16*)p;  p += (size_t)NB * NW * 128 * 2;
    u16* f1  = (u16*)p;  p += (size_t)128 * 512 * 2;
    u16* f2  = (u16*)p;  p += (size_t)128 * 512 * 2;
    u16* gt1 = (u16*)p;  p += (size_t)512 * 128 * 2;
    u16* gt2 = (u16*)p;  p += (size_t)512 * 128 * 2;
    u16* wr1 = (u16*)p;  p += (size_t)NLAY * NM * NW * NW * 2;
    u16* wr2 = (u16*)p;  p += (size_t)NLAY * NM * NW * NW * 2;
    u16* wi1 = (u16*)p;  p += (size_t)NLAY * NM * NW * NW * 2;
    u16* wi2 = (u16*)p;  p += (size_t)NLAY * NM * NW * NW * 2;
    u16* cw1 = (u16*)p;  p += (size_t)NLAY * NW * NW * 2;
    u16* cw2 = (u16*)p;  p += (size_t)NLAY * NW * NW * 2;
    u16* f11 = (u16*)p;  p += (size_t)256 * 128 * 2;
    u16* f12 = (u16*)p;  p += (size_t)256 * 128 * 2;

    const size_t htplane = (size_t)NB * NR * NW;

    setup_misc<<<2176, 256, 0, stream>>>(z, conv_w, fc1_w, f1, f2, gt1, gt2,
                                         cw1, cw2, f11, f12, seq);
    prep_specw<<<512, 256, 0, stream>>>(spec_wr, spec_wi, wr1, wr2, wi1, wi2);
    fc0_kernel<<<dim3(8, 32), 256, 0, stream>>>(seq, t_grid, fc0_w, fc0_b,
                                                ht1, ht2, htc1, htc2, 0);

    for (int step = 0; step < NSTEPS; step++) {
        int cur = 0;
        for (int l = 0; l < NLAY; l++) {
            const u16* hc1 = ht1 + (size_t)cur * htplane;
            const u16* hc2 = ht2 + (size_t)cur * htplane;
            u16* hn1 = ht1 + (size_t)(cur ^ 1) * htplane;
            u16* hn2 = ht2 + (size_t)(cur ^ 1) * htplane;
            dft_mfma<<<dim3(128, 4), 256, 0, stream>>>(f1, f2, htc1, htc2, x1, x2);
            modemix_mfma<<<dim3(64, 4), 256, 0, stream>>>(x1, x2, wr1, wr2, wi1, wi2,
                                                          y1, y2, l);
            if (l < 3) {
                idft_conv_mfma<<<dim3(8, 2, 32), 256, 0, stream>>>(y1, y2, gt1, gt2,
                                                                   hc1, hc2, cw1, cw2,
                                                                   conv_b, hn1, hn2,
                                                                   htc1, htc2, l);
            } else {
                idft_head_mfma<<<dim3(8, 32), 256, 0, stream>>>(
                    y1, y2, gt1, gt2, hc1, hc2, cw1, cw2, conv_b,
                    f11, f12, fc1_b, fc2_w, fc2_b, t_grid, fc0_w, fc0_b,
                    seq, preds, ht1, ht2, htc1, htc2,
                    l, step, (step < NSTEPS - 1) ? 1 : 0);
            }
            cur ^= 1;
        }
    }
}

// Round 17
// 1675.000 us; speedup vs baseline: 2.1214x; 1.0118x over previous
//
#include <hip/hip_runtime.h>
#include <math.h>

// LatentFNO: B=32, T=24, R=512, W=128, M=64 modes, 4 layers, 12 steps.
// Round 17: XCD-locality swizzle — idft grids flattened with b in the LOW
// bits (linear%8 == b%8) so all rt/ot blocks of one batch b colocate on
// one XCD; y[b] (read 8-16x) becomes L2-resident instead of L3. Also
// prefetch seq[step+23] (zlast) before the head GEMM. Pure scheduling;
// bit-identical math (exact 3-term bf16 split A1B1+A1B2+A2B1).

#define NB 32
#define NR 512
#define NW 128
#define NM 64
#define NTH 24
#define NLAY 4
#define NSTEPS 12
#define SEQROWS 36

typedef unsigned short u16;
typedef unsigned int u32;
typedef __attribute__((ext_vector_type(8))) short bf16x8;
typedef __attribute__((ext_vector_type(4))) float f32x4;
#define MFMA16(a, b, c) __builtin_amdgcn_mfma_f32_16x16x32_bf16((a), (b), (c), 0, 0, 0)

__device__ __forceinline__ float gelu_exact(float x) {
    return 0.5f * x * (1.0f + erff(x * 0.70710678118654752f));
}
__device__ __forceinline__ float bf2f(u16 u) {
    union { u32 i; float f; } v; v.i = ((u32)u) << 16; return v.f;
}
__device__ __forceinline__ u16 f2bf_hi(float x) {
    union { float f; u32 i; } v; v.f = x; return (u16)(v.i >> 16);
}
__device__ __forceinline__ u16 f2bf_lo(float x) {
    float h = bf2f(f2bf_hi(x));
    return f2bf_hi(x - h);
}
__device__ __forceinline__ bf16x8 negbf(bf16x8 a) {
#pragma unroll
    for (int i = 0; i < 8; i++) a[i] ^= (short)0x8000;
    return a;
}

// ---------------------------------------------------------------------------
// Merged setup: DFT/iDFT tables + conv_w planes + fc1t planes + seq init.
// ---------------------------------------------------------------------------
__global__ void setup_misc(const float* __restrict__ z, const float* __restrict__ conv_w,
                           const float* __restrict__ fc1_w,
                           u16* __restrict__ f1, u16* __restrict__ f2,
                           u16* __restrict__ gt1, u16* __restrict__ gt2,
                           u16* __restrict__ cw1, u16* __restrict__ cw2,
                           u16* __restrict__ f11, u16* __restrict__ f12,
                           float* __restrict__ seq) {
    int idx = blockIdx.x * 256 + threadIdx.x;
    if (idx < 65536) {
        int mc = idx >> 9, r = idx & 511, m = mc & 63;
        int p = (m * r) & 511;
        float a = (float)p * (1.0f / 256.0f);
        float c = cospif(a), s = sinpif(a);
        float Fv = (mc < 64) ? c : -s;
        float cm = (m == 0) ? (1.0f / 512.0f) : (2.0f / 512.0f);
        float Gv = (mc < 64) ? cm * c : ((m == 0) ? 0.0f : -cm * s);
        f1[idx] = f2bf_hi(Fv); f2[idx] = f2bf_lo(Fv);
        size_t g = (size_t)r * 128 + mc;
        gt1[g] = f2bf_hi(Gv); gt2[g] = f2bf_lo(Gv);
    } else if (idx < 131072) {
        int i = idx - 65536;
        float v = conv_w[i];
        cw1[i] = f2bf_hi(v); cw2[i] = f2bf_lo(v);
    } else if (idx < 163840) {
        int i = idx - 131072;          // j*128 + c
        int j = i >> 7, c = i & 127;
        float v = fc1_w[(size_t)c * 256 + j];
        f11[i] = f2bf_hi(v); f12[i] = f2bf_lo(v);
    } else {
        int i = idx - 163840;          // < 32*24*512
        int b = i / (NTH * NR);
        int rem = i - b * (NTH * NR);
        seq[(size_t)b * SEQROWS * NR + rem] = z[i];
    }
}

// spec_w (l,i,o,m) -> planes [l][m][o][i] hi/lo, coalesced both directions.
__global__ __launch_bounds__(256) void prep_specw(const float* __restrict__ wr, const float* __restrict__ wi,
                           u16* __restrict__ wr1, u16* __restrict__ wr2,
                           u16* __restrict__ wi1, u16* __restrict__ wi2) {
    __shared__ float tile[128][65];
    int l = blockIdx.x >> 7, o = blockIdx.x & 127;
    int tid = threadIdx.x;
    size_t sbase = (size_t)l * 1048576 + (size_t)o * 64;
    size_t dbase = (size_t)l * 64 * 16384 + (size_t)o * 128;
    for (int pass = 0; pass < 2; pass++) {
        const float* src = pass ? wi : wr;
        u16* d1 = pass ? wi1 : wr1;
        u16* d2 = pass ? wi2 : wr2;
        if (pass) __syncthreads();
        for (int e = tid; e < 8192; e += 256) {
            int i = e >> 6, m = e & 63;
            tile[i][m] = src[sbase + (size_t)i * 8192 + m];
        }
        __syncthreads();
        for (int e = tid; e < 4096; e += 256) {
            int m = e >> 6, i2 = (e & 63) * 2;
            float v0 = tile[i2][m], v1 = tile[i2 + 1][m];
            u32 hh = (u32)f2bf_hi(v0) | ((u32)f2bf_hi(v1) << 16);
            u32 ll = (u32)f2bf_lo(v0) | ((u32)f2bf_lo(v1) << 16);
            size_t d = dbase + (size_t)m * 16384 + i2;
            *(u32*)&d1[d] = hh;
            *(u32*)&d2[d] = ll;
        }
    }
}

// ---------------------------------------------------------------------------
// fc0 (fp32), step 0 only: writes ht[b][r][c] AND htc[b][c][r] planes.
// ---------------------------------------------------------------------------
__global__ __launch_bounds__(256) void fc0_kernel(const float* __restrict__ seq,
        const float* __restrict__ t_grid, const float* __restrict__ fc0_w,
        const float* __restrict__ fc0_b, u16* __restrict__ ht1, u16* __restrict__ ht2,
        u16* __restrict__ htc1, u16* __restrict__ htc2, int step) {
    __shared__ float wlds[28 * 128];
    __shared__ float blds[128];
    int b = blockIdx.y, rblk = blockIdx.x;
    int tid = threadIdx.x;
    for (int t = tid; t < 28 * 128; t += 256) wlds[t] = fc0_w[t];
    if (tid < 128) blds[tid] = fc0_b[tid];
    __syncthreads();
    int lane = tid & 63, wq = tid >> 6;
    int r = rblk * 64 + lane;
    float sv[24];
    const float* sp = seq + ((size_t)b * SEQROWS + step) * NR + r;
#pragma unroll
    for (int t = 0; t < 24; t++) sv[t] = sp[(size_t)t * NR];
    float tt = t_grid[b * 24 + 23] + (float)(step + 1);
    float ang24 = 6.28318530717958647692f * tt * (1.0f / 24.0f);
    float ang168 = 6.28318530717958647692f * tt * (1.0f / 168.0f);
    float s24 = sinf(ang24), c24 = cosf(ang24), s168 = sinf(ang168);
    float xc = (float)r * (1.0f / 511.0f);
    size_t rowoff = ((size_t)b * NR + r) * NW;
#pragma unroll 2
    for (int w0 = 0; w0 < 32; w0 += 2) {
        float acc2[2];
#pragma unroll
        for (int q = 0; q < 2; q++) {
            int w = wq * 32 + w0 + q;
            float acc = blds[w];
#pragma unroll
            for (int t = 0; t < 24; t++) acc += sv[t] * wlds[t * 128 + w];
            acc += s24 * wlds[24 * 128 + w] + c24 * wlds[25 * 128 + w]
                 + s168 * wlds[26 * 128 + w] + xc * wlds[27 * 128 + w];
            acc2[q] = acc;
        }
        u16 h0 = f2bf_hi(acc2[0]), h1 = f2bf_hi(acc2[1]);
        u16 l0 = f2bf_lo(acc2[0]), l1 = f2bf_lo(acc2[1]);
        size_t off = rowoff + wq * 32 + w0;
        *(u32*)&ht1[off] = (u32)h0 | ((u32)h1 << 16);
        *(u32*)&ht2[off] = (u32)l0 | ((u32)l1 << 16);
        int w = wq * 32 + w0;
        size_t coff = ((size_t)b * 128 + w) * 512 + r;
        htc1[coff] = h0; htc1[coff + 512] = h1;
        htc2[coff] = l0; htc2[coff + 512] = l1;
    }
}

// ---------------------------------------------------------------------------
// dft (MFMA): X[128][4096] = F * htc^T, K=512, BK=64, depth-3 pipelined.
// grid (128 n-tiles of 32, 4 mc-tiles) = 512 blocks (2/CU).
// ---------------------------------------------------------------------------
__global__ __launch_bounds__(256) void dft_mfma(const u16* __restrict__ f1, const u16* __restrict__ f2,
        const u16* __restrict__ htc1, const u16* __restrict__ htc2,
        u16* __restrict__ x1, u16* __restrict__ x2) {
    __shared__ __align__(16) u16 A1[2][32 * 72], A2[2][32 * 72];
    __shared__ __align__(16) u16 B1[2][32 * 72], B2[2][32 * 72];
    int bx = blockIdx.x;
    int mct = blockIdx.y * 32;
    int tid = threadIdx.x, wid = tid >> 6, l = tid & 63;
    int wm0 = (wid >> 1) * 16, wn0 = (wid & 1) * 16;
    int arow = l & 15, kgrp = (l >> 4) * 8;
    f32x4 acc = {0.f, 0.f, 0.f, 0.f};
    int pl = tid >> 7, row = (tid >> 2) & 31, sp = (tid & 3) * 16;
    const u16* asrc = (pl ? f2 : f1) + (size_t)(mct + row) * 512 + sp;
    const u16* bsrc = (pl ? htc2 : htc1)
                      + ((size_t)(bx >> 2) * 128 + (bx & 3) * 32 + row) * 512 + sp;
    int loff = row * 72 + sp;
    u16* ad0 = (pl ? A2[0] : A1[0]) + loff;  u16* ad1 = (pl ? A2[1] : A1[1]) + loff;
    u16* bd0 = (pl ? B2[0] : B1[0]) + loff;  u16* bd1 = (pl ? B2[1] : B1[1]) + loff;
    uint4 oA0, oA1, oB0, oB1, eA0, eA1, eB0, eB1;
    oA0 = *(const uint4*)(asrc);     oA1 = *(const uint4*)(asrc + 8);
    oB0 = *(const uint4*)(bsrc);     oB1 = *(const uint4*)(bsrc + 8);
    *(uint4*)ad0 = oA0; *(uint4*)(ad0 + 8) = oA1;
    *(uint4*)bd0 = oB0; *(uint4*)(bd0 + 8) = oB1;
    oA0 = *(const uint4*)(asrc + 64);  oA1 = *(const uint4*)(asrc + 72);
    oB0 = *(const uint4*)(bsrc + 64);  oB1 = *(const uint4*)(bsrc + 72);
    eA0 = *(const uint4*)(asrc + 128); eA1 = *(const uint4*)(asrc + 136);
    eB0 = *(const uint4*)(bsrc + 128); eB1 = *(const uint4*)(bsrc + 136);
    __syncthreads();
#define DFT_COMPUTE(BUF)                                                       \
    { _Pragma("unroll")                                                        \
      for (int kk = 0; kk < 64; kk += 32) {                                    \
        bf16x8 a1 = *(const bf16x8*)&A1[BUF][(wm0 + arow) * 72 + kk + kgrp];   \
        bf16x8 a2 = *(const bf16x8*)&A2[BUF][(wm0 + arow) * 72 + kk + kgrp];   \
        bf16x8 b1 = *(const bf16x8*)&B1[BUF][(wn0 + arow) * 72 + kk + kgrp];   \
        bf16x8 b2 = *(const bf16x8*)&B2[BUF][(wn0 + arow) * 72 + kk + kgrp];   \
        acc = MFMA16(a1, b1, acc);                                             \
        acc = MFMA16(a1, b2, acc);                                             \
        acc = MFMA16(a2, b1, acc);                                             \
      } }
    for (int k = 0; k < 8; k += 2) {
        DFT_COMPUTE(0)
        *(uint4*)ad1 = oA0; *(uint4*)(ad1 + 8) = oA1;
        *(uint4*)bd1 = oB0; *(uint4*)(bd1 + 8) = oB1;
        if (k < 5) {
            int ko = (k + 3) * 64;
            oA0 = *(const uint4*)(asrc + ko);      oA1 = *(const uint4*)(asrc + ko + 8);
            oB0 = *(const uint4*)(bsrc + ko);      oB1 = *(const uint4*)(bsrc + ko + 8);
        }
        __syncthreads();
        DFT_COMPUTE(1)
        if (k < 6) {
            *(uint4*)ad0 = eA0; *(uint4*)(ad0 + 8) = eA1;
            *(uint4*)bd0 = eB0; *(uint4*)(bd0 + 8) = eB1;
            if (k < 4) {
                int ko = (k + 4) * 64;
                eA0 = *(const uint4*)(asrc + ko);  eA1 = *(const uint4*)(asrc + ko + 8);
                eB0 = *(const uint4*)(bsrc + ko);  eB1 = *(const uint4*)(bsrc + ko + 8);
            }
        }
        __syncthreads();
    }
#undef DFT_COMPUTE
    int mcr = mct + wm0 + (l >> 4) * 4;
    int n0 = bx * 32 + wn0 + (l & 15);
#pragma unroll
    for (int j = 0; j < 4; j++) {
        size_t o0 = (size_t)(mcr + j) * 4096 + n0;
        x1[o0] = f2bf_hi(acc[j]); x2[o0] = f2bf_lo(acc[j]);
    }
}

// ---------------------------------------------------------------------------
// modemix (MFMA, single-barrier): Y = W *c X per mode, K=128 fully in LDS.
// grid (64 m, 4 oq), 256 thr. (oq copies of mode m already XCD-colocated.)
// ---------------------------------------------------------------------------
__global__ __launch_bounds__(256) void modemix_mfma(const u16* __restrict__ x1, const u16* __restrict__ x2,
        const u16* __restrict__ wr1, const u16* __restrict__ wr2,
        const u16* __restrict__ wi1, const u16* __restrict__ wi2,
        u16* __restrict__ y1, u16* __restrict__ y2, int layer) {
    __shared__ __align__(16) u16 POOL[8 * 32 * 136];
    int m = blockIdx.x, oq = blockIdx.y;
    int tid = threadIdx.x, wid = tid >> 6, l = tid & 63;
    int wo0 = (wid >> 1) * 16, wb0 = (wid & 1) * 16;
    int arow = l & 15, kgrp = (l >> 4) * 8;
    size_t wbase = (((size_t)layer * 64 + m) * 128 + oq * 32) * 128;
#pragma unroll
    for (int q = 0; q < 16; q++) {
        const int slab = q >> 1;
        int rr = ((q & 1) << 4) + (tid >> 4);
        int seg = tid & 15;
        const u16* src;
        if      (slab == 0) src = wr1 + wbase + (size_t)rr * 128 + seg * 8;
        else if (slab == 1) src = wr2 + wbase + (size_t)rr * 128 + seg * 8;
        else if (slab == 2) src = wi1 + wbase + (size_t)rr * 128 + seg * 8;
        else if (slab == 3) src = wi2 + wbase + (size_t)rr * 128 + seg * 8;
        else if (slab == 4) src = x1 + (size_t)m * 4096 + rr * 128 + seg * 8;
        else if (slab == 5) src = x2 + (size_t)m * 4096 + rr * 128 + seg * 8;
        else if (slab == 6) src = x1 + (size_t)(64 + m) * 4096 + rr * 128 + seg * 8;
        else                src = x2 + (size_t)(64 + m) * 4096 + rr * 128 + seg * 8;
        *(uint4*)&POOL[slab * 4352 + rr * 136 + seg * 8] = *(const uint4*)src;
    }
    __syncthreads();
    f32x4 ar = {0.f, 0.f, 0.f, 0.f}, ai = {0.f, 0.f, 0.f, 0.f};
    int aoB = (wo0 + arow) * 136 + kgrp;
    int boB = (wb0 + arow) * 136 + kgrp;
#pragma unroll
    for (int kg = 0; kg < 4; kg++) {
        int ao = aoB + kg * 32;
        int bo = boB + kg * 32;
        bf16x8 Wr1 = *(const bf16x8*)&POOL[0 * 4352 + ao];
        bf16x8 Wr2 = *(const bf16x8*)&POOL[1 * 4352 + ao];
        bf16x8 Wi1 = *(const bf16x8*)&POOL[2 * 4352 + ao];
        bf16x8 Wi2 = *(const bf16x8*)&POOL[3 * 4352 + ao];
        bf16x8 Xr1 = *(const bf16x8*)&POOL[4 * 4352 + bo];
        bf16x8 Xr2 = *(const bf16x8*)&POOL[5 * 4352 + bo];
        bf16x8 Xi1 = *(const bf16x8*)&POOL[6 * 4352 + bo];
        bf16x8 Xi2 = *(const bf16x8*)&POOL[7 * 4352 + bo];
        bf16x8 nWi1 = negbf(Wi1), nWi2 = negbf(Wi2);
        ar = MFMA16(Wr1, Xr1, ar); ar = MFMA16(Wr1, Xr2, ar); ar = MFMA16(Wr2, Xr1, ar);
        ar = MFMA16(nWi1, Xi1, ar); ar = MFMA16(nWi1, Xi2, ar); ar = MFMA16(nWi2, Xi1, ar);
        ai = MFMA16(Wi1, Xr1, ai); ai = MFMA16(Wi1, Xr2, ai); ai = MFMA16(Wi2, Xr1, ai);
        ai = MFMA16(Wr1, Xi1, ai); ai = MFMA16(Wr1, Xi2, ai); ai = MFMA16(Wr2, Xi1, ai);
    }
    int ob = oq * 32 + wo0 + (l >> 4) * 4;
    int bb = wb0 + (l & 15);
#pragma unroll
    for (int j = 0; j < 4; j++) {
        size_t o = ((size_t)bb * 128 + ob + j) * 128;
        y1[o + m] = f2bf_hi(ar[j]); y2[o + m] = f2bf_lo(ar[j]);
        y1[o + 64 + m] = f2bf_hi(ai[j]); y2[o + 64 + m] = f2bf_lo(ai[j]);
    }
}

// ---------------------------------------------------------------------------
// idft+conv (layers 0..2): C[o][r] = [Y|CW](o,256)*[GT;ht](256,r)+bias,GELU.
// grid flat 512: bid = ((rt*2+ot)*32+b) -> bid%8 == b%8, so all 16 blocks
// of batch b share one XCD (y[b] L2-resident). T-epilogue writes htc.
// ---------------------------------------------------------------------------
__global__ __launch_bounds__(256) void idft_conv_mfma(const u16* __restrict__ y1, const u16* __restrict__ y2,
        const u16* __restrict__ gt1, const u16* __restrict__ gt2,
        const u16* __restrict__ hc1, const u16* __restrict__ hc2,
        const u16* __restrict__ cw1, const u16* __restrict__ cw2,
        const float* __restrict__ conv_b,
        u16* __restrict__ hn1, u16* __restrict__ hn2,
        u16* __restrict__ htc1, u16* __restrict__ htc2, int layer) {
    __shared__ __align__(16) u16 A1[2][2560], A2[2][2560];
    __shared__ __align__(16) u16 B1[2][2560], B2[2][2560];
    __shared__ __align__(16) u16 T1[64 * 66], T2[64 * 66];
    int bid = blockIdx.x;
    int b = bid & 31, ot = ((bid >> 5) & 1) * 64, rt = (bid >> 6) * 64;
    int tid = threadIdx.x, wid = tid >> 6, l = tid & 63;
    int wo0 = (wid >> 1) * 32, wr0 = (wid & 1) * 32;
    int arow = (l & 15), kgrp = (l >> 4) * 8;
    int srow = (tid >> 2) & 63, sseg = tid & 3;
    int soff = srow * 40 + sseg * 8;
    const u16* ya = y1 + ((size_t)b * 128 + ot + srow) * 128 + sseg * 8;
    const u16* yb = y2 + ((size_t)b * 128 + ot + srow) * 128 + sseg * 8;
    const u16* ca = cw1 + ((size_t)layer * 128 + ot + srow) * 128 + sseg * 8;
    const u16* cb = cw2 + ((size_t)layer * 128 + ot + srow) * 128 + sseg * 8;
    const u16* ga = gt1 + (size_t)(rt + srow) * 128 + sseg * 8;
    const u16* gb = gt2 + (size_t)(rt + srow) * 128 + sseg * 8;
    const u16* ha = hc1 + ((size_t)b * 512 + rt + srow) * 128 + sseg * 8;
    const u16* hb = hc2 + ((size_t)b * 512 + rt + srow) * 128 + sseg * 8;
    f32x4 acc[2][2] = {{{0.f,0.f,0.f,0.f},{0.f,0.f,0.f,0.f}},{{0.f,0.f,0.f,0.f},{0.f,0.f,0.f,0.f}}};
    uint4 raO0, raO1, rbO0, rbO1, raE0, raE1, rbE0, rbE1;
#define ILOAD(chk, Ra0, Ra1, Rb0, Rb1)                                        \
    {   int k0_ = ((chk) & 3) * 32;                                           \
        if ((chk) < 4) {                                                      \
            Ra0 = *(const uint4*)(ya + k0_); Ra1 = *(const uint4*)(yb + k0_); \
            Rb0 = *(const uint4*)(ga + k0_); Rb1 = *(const uint4*)(gb + k0_); \
        } else {                                                              \
            Ra0 = *(const uint4*)(ca + k0_); Ra1 = *(const uint4*)(cb + k0_); \
            Rb0 = *(const uint4*)(ha + k0_); Rb1 = *(const uint4*)(hb + k0_); \
        } }
#define ISTORE(BUF, Ra0, Ra1, Rb0, Rb1)                                      \
    {   *(uint4*)(A1[BUF] + soff) = Ra0; *(uint4*)(A2[BUF] + soff) = Ra1;     \
        *(uint4*)(B1[BUF] + soff) = Rb0; *(uint4*)(B2[BUF] + soff) = Rb1; }
#define ICOMP(BUF)                                                            \
    {   bf16x8 bfr[2][2];                                                     \
        _Pragma("unroll")                                                     \
        for (int rf = 0; rf < 2; rf++) {                                      \
            bfr[rf][0] = *(const bf16x8*)&B1[BUF][(wr0 + rf * 16 + arow) * 40 + kgrp]; \
            bfr[rf][1] = *(const bf16x8*)&B2[BUF][(wr0 + rf * 16 + arow) * 40 + kgrp]; \
        }                                                                     \
        _Pragma("unroll")                                                     \
        for (int of = 0; of < 2; of++) {                                      \
            bf16x8 a1 = *(const bf16x8*)&A1[BUF][(wo0 + of * 16 + arow) * 40 + kgrp]; \
            bf16x8 a2 = *(const bf16x8*)&A2[BUF][(wo0 + of * 16 + arow) * 40 + kgrp]; \
            _Pragma("unroll")                                                 \
            for (int rf = 0; rf < 2; rf++) {                                  \
                acc[of][rf] = MFMA16(a1, bfr[rf][0], acc[of][rf]);            \
                acc[of][rf] = MFMA16(a1, bfr[rf][1], acc[of][rf]);            \
                acc[of][rf] = MFMA16(a2, bfr[rf][0], acc[of][rf]);            \
            }                                                                 \
        } }
    ILOAD(0, raO0, raO1, rbO0, rbO1)
    ISTORE(0, raO0, raO1, rbO0, rbO1)
    ILOAD(1, raO0, raO1, rbO0, rbO1)
    ILOAD(2, raE0, raE1, rbE0, rbE1)
    __syncthreads();
    for (int k = 0; k < 8; k += 2) {
        ICOMP(0)
        ISTORE(1, raO0, raO1, rbO0, rbO1)
        if (k < 5) ILOAD(k + 3, raO0, raO1, rbO0, rbO1)
        __syncthreads();
        ICOMP(1)
        if (k < 6) {
            ISTORE(0, raE0, raE1, rbE0, rbE1)
            if (k < 4) ILOAD(k + 4, raE0, raE1, rbE0, rbE1)
        }
        __syncthreads();
    }
#undef ILOAD
#undef ISTORE
#undef ICOMP
#pragma unroll
    for (int of = 0; of < 2; of++) {
        int obl = wo0 + of * 16 + (l >> 4) * 4;
        int ob = ot + obl;
#pragma unroll
        for (int rf = 0; rf < 2; rf++) {
            int rloc = wr0 + rf * 16 + (l & 15);
            int r = rt + rloc;
            float v0 = gelu_exact(acc[of][rf][0] + conv_b[layer * 128 + ob + 0]);
            float v1 = gelu_exact(acc[of][rf][1] + conv_b[layer * 128 + ob + 1]);
            float v2 = gelu_exact(acc[of][rf][2] + conv_b[layer * 128 + ob + 2]);
            float v3 = gelu_exact(acc[of][rf][3] + conv_b[layer * 128 + ob + 3]);
            ushort4 hv, lv;
            hv.x = f2bf_hi(v0); hv.y = f2bf_hi(v1); hv.z = f2bf_hi(v2); hv.w = f2bf_hi(v3);
            lv.x = f2bf_lo(v0); lv.y = f2bf_lo(v1); lv.z = f2bf_lo(v2); lv.w = f2bf_lo(v3);
            size_t off = ((size_t)b * 512 + r) * 128 + ob;
            *(ushort4*)&hn1[off] = hv;
            *(ushort4*)&hn2[off] = lv;
            T1[(obl + 0) * 66 + rloc] = hv.x; T1[(obl + 1) * 66 + rloc] = hv.y;
            T1[(obl + 2) * 66 + rloc] = hv.z; T1[(obl + 3) * 66 + rloc] = hv.w;
            T2[(obl + 0) * 66 + rloc] = lv.x; T2[(obl + 1) * 66 + rloc] = lv.y;
            T2[(obl + 2) * 66 + rloc] = lv.z; T2[(obl + 3) * 66 + rloc] = lv.w;
        }
    }
    __syncthreads();
#pragma unroll
    for (int q = 0; q < 8; q++) {
        int t = tid + q * 256;
        int o = t >> 5, ru = t & 31;
        u32 vh = *(const u32*)&T1[o * 66 + ru * 2];
        u32 vl = *(const u32*)&T2[o * 66 + ru * 2];
        size_t off = ((size_t)b * 128 + ot + o) * 512 + rt + ru * 2;
        *(u32*)&htc1[off] = vh;
        *(u32*)&htc2[off] = vl;
    }
}

// ---------------------------------------------------------------------------
// Layer-3 fused: idft+conv (all 128 o) -> h in LDS -> head (pipelined fc1t
// staging) -> z update -> fc0 next step. grid flat 256: bid = rt*32+b
// (bid%8 == b%8: same-b blocks share XCD -> y[b] L2-resident).
// ---------------------------------------------------------------------------
__global__ __launch_bounds__(256) void idft_head_mfma(
        const u16* __restrict__ y1, const u16* __restrict__ y2,
        const u16* __restrict__ gt1, const u16* __restrict__ gt2,
        const u16* __restrict__ hc1, const u16* __restrict__ hc2,
        const u16* __restrict__ cw1, const u16* __restrict__ cw2,
        const float* __restrict__ conv_b,
        const u16* __restrict__ f11, const u16* __restrict__ f12,
        const float* __restrict__ fc1_b, const float* __restrict__ fc2_w,
        const float* __restrict__ fc2_b,
        const float* __restrict__ t_grid, const float* __restrict__ fc0_w,
        const float* __restrict__ fc0_b,
        float* __restrict__ seq, float* __restrict__ preds,
        u16* __restrict__ nht1, u16* __restrict__ nht2,
        u16* __restrict__ nhtc1, u16* __restrict__ nhtc2,
        int layer, int step, int do_fc0) {
    __shared__ __align__(16) u16 POOL[35072];   // 70144 B
    int bid = blockIdx.x;
    int b = bid & 31, rt = (bid >> 5) * 64;
    int tid = threadIdx.x, wid = tid >> 6, l = tid & 63;
    int wo0 = (wid >> 1) * 32, wr0 = (wid & 1) * 32;
    int arow = (l & 15), kgrp = (l >> 4) * 8;
    // early zlast prefetch (independent of everything below)
    bool zlane = ((l >> 4) == 0);
    int rml = wid * 16 + arow;
    float zlast = 0.0f;
    if (zlane) zlast = seq[((size_t)b * SEQROWS + step + 23) * NR + rt + rml];
    u16* A1 = POOL;                  // [2][5120]
    u16* A2 = POOL + 10240;
    u16* B1 = POOL + 20480;          // [2][2560]
    u16* B2 = POOL + 25600;
    int srow = tid >> 2, sseg = tid & 3;
    const u16* ya0 = y1 + ((size_t)b * 128 + srow) * 128 + sseg * 8;
    const u16* ya1 = ya0 + 64 * 128;
    const u16* yb0 = y2 + ((size_t)b * 128 + srow) * 128 + sseg * 8;
    const u16* yb1 = yb0 + 64 * 128;
    const u16* ca0 = cw1 + ((size_t)layer * 128 + srow) * 128 + sseg * 8;
    const u16* ca1 = ca0 + 64 * 128;
    const u16* cb0 = cw2 + ((size_t)layer * 128 + srow) * 128 + sseg * 8;
    const u16* cb1 = cb0 + 64 * 128;
    const u16* ga = gt1 + (size_t)(rt + srow) * 128 + sseg * 8;
    const u16* gb = gt2 + (size_t)(rt + srow) * 128 + sseg * 8;
    const u16* ha = hc1 + ((size_t)b * 512 + rt + srow) * 128 + sseg * 8;
    const u16* hb = hc2 + ((size_t)b * 512 + rt + srow) * 128 + sseg * 8;
    int soffA0 = srow * 40 + sseg * 8;
    int soffA1 = (srow + 64) * 40 + sseg * 8;
    f32x4 acc[2][2][2];
#pragma unroll
    for (int ot = 0; ot < 2; ot++)
#pragma unroll
        for (int of = 0; of < 2; of++)
#pragma unroll
            for (int rf = 0; rf < 2; rf++) acc[ot][of][rf] = (f32x4){0.f, 0.f, 0.f, 0.f};
    uint4 oA0, oA1r, oA2r, oA3, oB0, oB1;
    uint4 eA0, eA1r, eA2r, eA3, eB0, eB1;
#define ILOAD(chk, Q0, Q1, Q2, Q3, R0, R1)                                    \
    {   int k0_ = ((chk) & 3) * 32;                                           \
        if ((chk) < 4) {                                                      \
            Q0 = *(const uint4*)(ya0 + k0_); Q1 = *(const uint4*)(ya1 + k0_); \
            Q2 = *(const uint4*)(yb0 + k0_); Q3 = *(const uint4*)(yb1 + k0_); \
            R0 = *(const uint4*)(ga + k0_);  R1 = *(const uint4*)(gb + k0_);  \
        } else {                                                              \
            Q0 = *(const uint4*)(ca0 + k0_); Q1 = *(const uint4*)(ca1 + k0_); \
            Q2 = *(const uint4*)(cb0 + k0_); Q3 = *(const uint4*)(cb1 + k0_); \
            R0 = *(const uint4*)(ha + k0_);  R1 = *(const uint4*)(hb + k0_);  \
        } }
#define ISTORE(BUF, Q0, Q1, Q2, Q3, R0, R1)                                   \
    {   *(uint4*)(A1 + (BUF) * 5120 + soffA0) = Q0;                           \
        *(uint4*)(A1 + (BUF) * 5120 + soffA1) = Q1;                           \
        *(uint4*)(A2 + (BUF) * 5120 + soffA0) = Q2;                           \
        *(uint4*)(A2 + (BUF) * 5120 + soffA1) = Q3;                           \
        *(uint4*)(B1 + (BUF) * 2560 + soffA0) = R0;                           \
        *(uint4*)(B2 + (BUF) * 2560 + soffA0) = R1; }
#define ICOMP(BUF)                                                            \
    {   bf16x8 bfr[2][2];                                                     \
        _Pragma("unroll")                                                     \
        for (int rf = 0; rf < 2; rf++) {                                      \
            bfr[rf][0] = *(const bf16x8*)&B1[(BUF) * 2560 + (wr0 + rf * 16 + arow) * 40 + kgrp]; \
            bfr[rf][1] = *(const bf16x8*)&B2[(BUF) * 2560 + (wr0 + rf * 16 + arow) * 40 + kgrp]; \
        }                                                                     \
        _Pragma("unroll")                                                     \
        for (int ot = 0; ot < 2; ot++) {                                      \
        _Pragma("unroll")                                                     \
        for (int of = 0; of < 2; of++) {                                      \
            bf16x8 a1v = *(const bf16x8*)&A1[(BUF) * 5120 + (ot * 64 + wo0 + of * 16 + arow) * 40 + kgrp]; \
            bf16x8 a2v = *(const bf16x8*)&A2[(BUF) * 5120 + (ot * 64 + wo0 + of * 16 + arow) * 40 + kgrp]; \
            _Pragma("unroll")                                                 \
            for (int rf = 0; rf < 2; rf++) {                                  \
                acc[ot][of][rf] = MFMA16(a1v, bfr[rf][0], acc[ot][of][rf]);   \
                acc[ot][of][rf] = MFMA16(a1v, bfr[rf][1], acc[ot][of][rf]);   \
                acc[ot][of][rf] = MFMA16(a2v, bfr[rf][0], acc[ot][of][rf]);   \
            }                                                                 \
        } } }
    ILOAD(0, oA0, oA1r, oA2r, oA3, oB0, oB1)
    ISTORE(0, oA0, oA1r, oA2r, oA3, oB0, oB1)
    ILOAD(1, oA0, oA1r, oA2r, oA3, oB0, oB1)
    ILOAD(2, eA0, eA1r, eA2r, eA3, eB0, eB1)
    __syncthreads();
    for (int k = 0; k < 8; k += 2) {
        ICOMP(0)
        ISTORE(1, oA0, oA1r, oA2r, oA3, oB0, oB1)
        if (k < 5) ILOAD(k + 3, oA0, oA1r, oA2r, oA3, oB0, oB1)
        __syncthreads();
        ICOMP(1)
        if (k < 6) {
            ISTORE(0, eA0, eA1r, eA2r, eA3, eB0, eB1)
            if (k < 4) ILOAD(k + 4, eA0, eA1r, eA2r, eA3, eB0, eB1)
        }
        __syncthreads();
    }
#undef ILOAD
#undef ISTORE
#undef ICOMP
    __syncthreads();                 // A/B reads done; alias h over POOL
    u16* h1 = POOL;                  // [64][136] hi
    u16* h2 = POOL + 8704;           // [64][136] lo
#pragma unroll
    for (int ot = 0; ot < 2; ot++) {
#pragma unroll
        for (int of = 0; of < 2; of++) {
            int obl = ot * 64 + wo0 + of * 16 + (l >> 4) * 4;
#pragma unroll
            for (int rf = 0; rf < 2; rf++) {
                int rloc = wr0 + rf * 16 + (l & 15);
                float v0 = gelu_exact(acc[ot][of][rf][0] + conv_b[layer * 128 + obl + 0]);
                float v1 = gelu_exact(acc[ot][of][rf][1] + conv_b[layer * 128 + obl + 1]);
                float v2 = gelu_exact(acc[ot][of][rf][2] + conv_b[layer * 128 + obl + 2]);
                float v3 = gelu_exact(acc[ot][of][rf][3] + conv_b[layer * 128 + obl + 3]);
                ushort4 hv, lv;
                hv.x = f2bf_hi(v0); hv.y = f2bf_hi(v1); hv.z = f2bf_hi(v2); hv.w = f2bf_hi(v3);
                lv.x = f2bf_lo(v0); lv.y = f2bf_lo(v1); lv.z = f2bf_lo(v2); lv.w = f2bf_lo(v3);
                *(ushort4*)&h1[rloc * 136 + obl] = hv;
                *(ushort4*)&h2[rloc * 136 + obl] = lv;
            }
        }
    }
    // ---- head: D[j][r] = fc1t(j,c)*h(r,c); dx = sum_j gelu(D+b1)*w2 ----
    u16* HA1 = POOL + 17408;         // [128][40]
    u16* HA2 = POOL + 22528;
    float* fc2s = (float*)(POOL + 27648);    // 256 f
    float* fc1bs = (float*)(POOL + 28160);   // 256 f
    fc2s[tid] = fc2_w[tid];
    fc1bs[tid] = fc1_b[tid];
    int j0 = tid >> 2, segh = tid & 3;
    const u16* fa = f11 + (size_t)j0 * 128 + segh * 8;
    const u16* fb = f12 + (size_t)j0 * 128 + segh * 8;
    int haoff = j0 * 40 + segh * 8;
    uint4 pr0, pr1, pr2, pr3;
#define HLOAD(JH, K0)                                                         \
    {   size_t o_ = (size_t)(JH) * 128 * 128 + (K0);                          \
        pr0 = *(const uint4*)(fa + o_);                                       \
        pr1 = *(const uint4*)(fa + o_ + 64 * 128);                            \
        pr2 = *(const uint4*)(fb + o_);                                       \
        pr3 = *(const uint4*)(fb + o_ + 64 * 128); }
#define HSTORE()                                                              \
    {   *(uint4*)(HA1 + haoff) = pr0;                                         \
        *(uint4*)(HA1 + haoff + 64 * 40) = pr1;                               \
        *(uint4*)(HA2 + haoff) = pr2;                                         \
        *(uint4*)(HA2 + haoff + 64 * 40) = pr3; }
    float dx = 0.0f;
    HLOAD(0, 0)
    for (int jh = 0; jh < 2; jh++) {
        f32x4 hacc[8];
#pragma unroll
        for (int jf = 0; jf < 8; jf++) hacc[jf] = (f32x4){0.f, 0.f, 0.f, 0.f};
        for (int k0 = 0; k0 < 128; k0 += 32) {
            __syncthreads();
            HSTORE()
            __syncthreads();
            if (k0 < 96) { HLOAD(jh, k0 + 32) }
            else if (jh == 0) { HLOAD(1, 0) }
            int bo = (wid * 16 + arow) * 136 + k0 + kgrp;
            bf16x8 hb1 = *(const bf16x8*)&h1[bo];
            bf16x8 hb2 = *(const bf16x8*)&h2[bo];
#pragma unroll
            for (int jf = 0; jf < 8; jf++) {
                int ao = (jf * 16 + arow) * 40 + kgrp;
                bf16x8 a1 = *(const bf16x8*)&HA1[ao];
                bf16x8 a2 = *(const bf16x8*)&HA2[ao];
                hacc[jf] = MFMA16(a1, hb1, hacc[jf]);
                hacc[jf] = MFMA16(a1, hb2, hacc[jf]);
                hacc[jf] = MFMA16(a2, hb1, hacc[jf]);
            }
        }
#pragma unroll
        for (int jf = 0; jf < 8; jf++) {
            int jbase = jh * 128 + jf * 16 + (l >> 4) * 4;
#pragma unroll
            for (int jj = 0; jj < 4; jj++) {
                dx += gelu_exact(hacc[jf][jj] + fc1bs[jbase + jj]) * fc2s[jbase + jj];
            }
        }
    }
#undef HLOAD
#undef HSTORE
    // prefetch fc0-tail inputs into registers (independent of zn)
    float winreg[6], wlreg[14], blreg = 0.0f;
    if (do_fc0) {
#pragma unroll
        for (int q = 0; q < 6; q++) {
            int t2 = tid + q * 256;
            winreg[q] = 0.0f;
            if (t2 < 1472) {
                int tr = t2 >> 6, c = t2 & 63;
                winreg[q] = seq[((size_t)b * SEQROWS + step + 1 + tr) * NR + rt + c];
            }
        }
#pragma unroll
        for (int q = 0; q < 14; q++) wlreg[q] = fc0_w[tid + q * 256];
        if (tid < 128) blreg = fc0_b[tid];
    }
    dx += __shfl_xor(dx, 16);
    dx += __shfl_xor(dx, 32);
    float zn = 0.0f;
    if (zlane) {
        int r = rt + rml;
        zn = zlast + dx + fc2_b[0];
        seq[((size_t)b * SEQROWS + step + 24) * NR + r] = zn;
        preds[((size_t)b * NSTEPS + step) * NR + r] = zn;
    }
    if (do_fc0) {
        float* win = (float*)POOL;                 // [24][64]
        float* wl  = (float*)POOL + 2048;          // [28][128]
        float* bl  = (float*)POOL + 2048 + 3584;   // [128]
        __syncthreads();   // all h/HA LDS reads done before aliasing
#pragma unroll
        for (int q = 0; q < 6; q++) {
            int t2 = tid + q * 256;
            if (t2 < 1472) win[t2] = winreg[q];
        }
#pragma unroll
        for (int q = 0; q < 14; q++) wl[tid + q * 256] = wlreg[q];
        if (tid < 128) bl[tid] = blreg;
        if (zlane) win[23 * 64 + rml] = zn;
        __syncthreads();
        int lane = tid & 63, wq = tid >> 6;
        int r = rt + lane;
        float sv[24];
#pragma unroll
        for (int t = 0; t < 24; t++) sv[t] = win[t * 64 + lane];
        float tt = t_grid[b * 24 + 23] + (float)(step + 2);
        float ang24 = 6.28318530717958647692f * tt * (1.0f / 24.0f);
        float ang168 = 6.28318530717958647692f * tt * (1.0f / 168.0f);
        float s24 = sinf(ang24), c24 = cosf(ang24), s168 = sinf(ang168);
        float xc = (float)r * (1.0f / 511.0f);
        size_t rowoff = ((size_t)b * NR + r) * NW;
#pragma unroll 2
        for (int w0 = 0; w0 < 32; w0 += 2) {
            float acc2[2];
#pragma unroll
            for (int q = 0; q < 2; q++) {
                int w = wq * 32 + w0 + q;
                float a = bl[w];
#pragma unroll
                for (int t = 0; t < 24; t++) a += sv[t] * wl[t * 128 + w];
                a += s24 * wl[24 * 128 + w] + c24 * wl[25 * 128 + w]
                   + s168 * wl[26 * 128 + w] + xc * wl[27 * 128 + w];
                acc2[q] = a;
            }
            u16 h0 = f2bf_hi(acc2[0]), h1v = f2bf_hi(acc2[1]);
            u16 l0 = f2bf_lo(acc2[0]), l1v = f2bf_lo(acc2[1]);
            size_t off = rowoff + wq * 32 + w0;
            *(u32*)&nht1[off] = (u32)h0 | ((u32)h1v << 16);
            *(u32*)&nht2[off] = (u32)l0 | ((u32)l1v << 16);
            int w = wq * 32 + w0;
            size_t coff = ((size_t)b * 128 + w) * 512 + r;
            nhtc1[coff] = h0; nhtc1[coff + 512] = h1v;
            nhtc2[coff] = l0; nhtc2[coff + 512] = l1v;
        }
    }
}

// ---------------------------------------------------------------------------
extern "C" void kernel_launch(void* const* d_in, const int* in_sizes, int n_in,
                              void* d_out, int out_size, void* d_ws, size_t ws_size,
                              hipStream_t stream) {
    (void)in_sizes; (void)n_in; (void)out_size; (void)ws_size;
    const float* z       = (const float*)d_in[0];
    const float* t_grid  = (const float*)d_in[1];
    const float* fc0_w   = (const float*)d_in[2];
    const float* fc0_b   = (const float*)d_in[3];
    const float* spec_wr = (const float*)d_in[4];
    const float* spec_wi = (const float*)d_in[5];
    const float* conv_w  = (const float*)d_in[6];
    const float* conv_b  = (const float*)d_in[7];
    const float* fc1_w   = (const float*)d_in[8];
    const float* fc1_b   = (const float*)d_in[9];
    const float* fc2_w   = (const float*)d_in[10];
    const float* fc2_b   = (const float*)d_in[11];
    float* preds = (float*)d_out;

    char* p = (char*)d_ws;
    float* seq = (float*)p;  p += (size_t)NB * SEQROWS * NR * 4;
    u16* ht1 = (u16*)p;  p += (size_t)2 * NB * NR * NW * 2;   // [2 buf][b][r][c] hi
    u16* ht2 = (u16*)p;  p += (size_t)2 * NB * NR * NW * 2;   // lo
    u16* htc1 = (u16*)p; p += (size_t)NB * NW * NR * 2;       // [b][c][r] hi
    u16* htc2 = (u16*)p; p += (size_t)NB * NW * NR * 2;       // lo
    u16* x1  = (u16*)p;  p += (size_t)128 * 4096 * 2;
    u16* x2  = (u16*)p;  p += (size_t)128 * 4096 * 2;
    u16* y1  = (u16*)p;  p += (size_t)NB * NW * 128 * 2;
    u16* y2  = (u16*)p;  p += (size_t)NB * NW * 128 * 2;
    u16* f1  = (u16*)p;  p += (size_t)128 * 512 * 2;
    u16* f2  = (u16*)p;  p += (size_t)128 * 512 * 2;
    u16* gt1 = (u16*)p;  p += (size_t)512 * 128 * 2;
    u16* gt2 = (u16*)p;  p += (size_t)512 * 128 * 2;
    u16* wr1 = (u16*)p;  p += (size_t)NLAY * NM * NW * NW * 2;
    u16* wr2 = (u16*)p;  p += (size_t)NLAY * NM * NW * NW * 2;
    u16* wi1 = (u16*)p;  p += (size_t)NLAY * NM * NW * NW * 2;
    u16* wi2 = (u16*)p;  p += (size_t)NLAY * NM * NW * NW * 2;
    u16* cw1 = (u16*)p;  p += (size_t)NLAY * NW * NW * 2;
    u16* cw2 = (u16*)p;  p += (size_t)NLAY * NW * NW * 2;
    u16* f11 = (u16*)p;  p += (size_t)256 * 128 * 2;
    u16* f12 = (u16*)p;  p += (size_t)256 * 128 * 2;

    const size_t htplane = (size_t)NB * NR * NW;

    setup_misc<<<2176, 256, 0, stream>>>(z, conv_w, fc1_w, f1, f2, gt1, gt2,
                                         cw1, cw2, f11, f12, seq);
    prep_specw<<<512, 256, 0, stream>>>(spec_wr, spec_wi, wr1, wr2, wi1, wi2);
    fc0_kernel<<<dim3(8, 32), 256, 0, stream>>>(seq, t_grid, fc0_w, fc0_b,
                                                ht1, ht2, htc1, htc2, 0);

    for (int step = 0; step < NSTEPS; step++) {
        int cur = 0;
        for (int l = 0; l < NLAY; l++) {
            const u16* hc1 = ht1 + (size_t)cur * htplane;
            const u16* hc2 = ht2 + (size_t)cur * htplane;
            u16* hn1 = ht1 + (size_t)(cur ^ 1) * htplane;
            u16* hn2 = ht2 + (size_t)(cur ^ 1) * htplane;
            dft_mfma<<<dim3(128, 4), 256, 0, stream>>>(f1, f2, htc1, htc2, x1, x2);
            modemix_mfma<<<dim3(64, 4), 256, 0, stream>>>(x1, x2, wr1, wr2, wi1, wi2,
                                                          y1, y2, l);
            if (l < 3) {
                idft_conv_mfma<<<dim3(512), 256, 0, stream>>>(y1, y2, gt1, gt2,
                                                              hc1, hc2, cw1, cw2,
                                                              conv_b, hn1, hn2,
                                                              htc1, htc2, l);
            } else {
                idft_head_mfma<<<dim3(256), 256, 0, stream>>>(
                    y1, y2, gt1, gt2, hc1, hc2, cw1, cw2, conv_b,
                    f11, f12, fc1_b, fc2_w, fc2_b, t_grid, fc0_w, fc0_b,
                    seq, preds, ht1, ht2, htc1, htc2,
                    l, step, (step < NSTEPS - 1) ? 1 : 0);
            }
            cur ^= 1;
        }
    }
}